// Round 7
// baseline (360.820 us; speedup 1.0000x reference)
//
#include <hip/hip_runtime.h>
#include <hip/hip_bf16.h>

typedef __attribute__((ext_vector_type(4))) float floatx4;
typedef __attribute__((ext_vector_type(8))) short shortx8;
typedef __attribute__((address_space(3))) void as3_void;
typedef const __attribute__((address_space(1))) void as1_void;

__device__ __forceinline__ unsigned short f2bf(float f) {
    unsigned int u; __builtin_memcpy(&u, &f, 4);
    u += 0x7FFFu + ((u >> 16) & 1u);   // RNE
    return (unsigned short)(u >> 16);
}
__device__ __forceinline__ float bf2f(unsigned short h) {
    unsigned int u = ((unsigned int)h) << 16;
    float f; __builtin_memcpy(&f, &u, 4); return f;
}
__device__ __forceinline__ shortx8 pack8(floatx4 lo, floatx4 hi) {
    shortx8 r;
    r[0] = (short)f2bf(lo[0]); r[1] = (short)f2bf(lo[1]);
    r[2] = (short)f2bf(lo[2]); r[3] = (short)f2bf(lo[3]);
    r[4] = (short)f2bf(hi[0]); r[5] = (short)f2bf(hi[1]);
    r[6] = (short)f2bf(hi[2]); r[7] = (short)f2bf(hi[3]);
    return r;
}
__device__ __forceinline__ void ld16(const unsigned short* g, unsigned short* l) {
    __builtin_amdgcn_global_load_lds((as1_void*)g, (as3_void*)l, 16, 0, 0);
}

#define BM 128
#define BN 128
#define BK 32

// ---------- fp32 -> bf16 pre-convert (now W-only: 864 blocks) ----------
__global__ __launch_bounds__(256) void cvt4(
    const float* __restrict__ s0, const float* __restrict__ s1,
    const float* __restrict__ s2, const float* __restrict__ s3,
    unsigned short* __restrict__ d0, unsigned short* __restrict__ d1,
    unsigned short* __restrict__ d2, unsigned short* __restrict__ d3,
    int nb0, int nb1, int nb2)
{
    int bid = blockIdx.x;
    const float* s; unsigned short* d;
    if (bid < nb0)                  { s = s0; d = d0; }
    else if (bid < nb0 + nb1)       { s = s1; d = d1; bid -= nb0; }
    else if (bid < nb0 + nb1 + nb2) { s = s2; d = d2; bid -= nb0 + nb1; }
    else                            { s = s3; d = d3; bid -= nb0 + nb1 + nb2; }
    const size_t i = ((size_t)bid * 256 + threadIdx.x) * 8;
    const floatx4 lo = *(const floatx4*)(s + i);
    const floatx4 hi = *(const floatx4*)(s + i + 4);
    *(shortx8*)(d + i) = pack8(lo, hi);
}

// ---------- GEMM v6: v3 stage-ahead pipeline + fp32-A reg-staging ----------
// q/k/v = X (M x K fp32, converted in-kernel) * Wb[z]^T (NxK bf16) + bias.
// 1D grid 3528 = 8*441; y-grouped XCD swizzle (FETCH 360->121 MB, round 1).
// v3 (131.6us, 675 TF) = documented minimum-2-phase ceiling. v6 keeps that
// schedule EXACTLY (1-ahead dbuf, one __syncthreads per 64-K tile) and
// removes the cvt4 X round-trip: A is loaded fp32 -> pack8 (same RNE as
// cvt4, bit-identical) -> ds_write_b128. T14 ordering: the 8 fp32 loads
// for tile t+1 are issued BEFORE compute(t); the pack+ds_write happens
// AFTER compute(t), so HBM latency hides under the 32-MFMA phase.
// B stays global_load_lds (bf16 W, pre-converted by the tiny cvt4).
// Round-4/6 lessons honored: no LDS swizzle (conflicts hidden here), no
// asm vmcnt / sched_barrier (compiler schedules better, m141).
__global__ __launch_bounds__(256) void gemm_qkv_bf16(
    const float* __restrict__ Xf,
    const unsigned short* __restrict__ Wb,   // 3 contiguous NxK bf16 mats
    const float* __restrict__ bq, const float* __restrict__ bk,
    const float* __restrict__ bv,
    unsigned short* __restrict__ Qb16,
    unsigned short* __restrict__ Kb, unsigned short* __restrict__ Vb,
    int M, int N, int K)
{
    // [buf][chunk(2) x BM x BK] : 16 KiB per buf per matrix = 64 KiB total
    __shared__ __attribute__((aligned(16))) unsigned short As[2][2 * BM * BK];
    __shared__ __attribute__((aligned(16))) unsigned short Bs[2][2 * BN * BK];

    // swizzled decode: w = y*18 + z*6 + x, chunked 441-per-XCD (bijective)
    const unsigned g    = blockIdx.x;
    const unsigned xcd  = g & 7u;
    const unsigned slot = g >> 3;                 // 0..440
    const unsigned w    = xcd * 441u + slot;      // y-grouped work index
    const unsigned yb   = w / 18u;                // M-tile 0..195
    const unsigned rr_  = w - yb * 18u;
    const unsigned z    = rr_ / 6u;               // 0..2
    const unsigned xb   = rr_ - z * 6u;           // N-tile 0..5

    const unsigned short* W = Wb + (size_t)z * N * K;
    const float* bias = (z == 0) ? bq : ((z == 1) ? bk : bv);

    const int tid  = threadIdx.x;
    const int wave = tid >> 6;
    const int lane = tid & 63;

    const int mBlock = (int)yb * BM;
    const int nBlock = (int)xb * BN;

    // staging map: thread t -> row t>>2 (and +64), 8-elem chunk (t&3)*8
    const int sRow   = tid >> 2;
    const int sChunk = (tid & 3) * 8;
    const float*          Ag = Xf + (size_t)(mBlock + sRow) * K + sChunk;
    const unsigned short* Bg = W  + (size_t)(nBlock + sRow) * K + sChunk;
    const int ldsOff = sRow * BK + sChunk;        // == tid*8, linear

    floatx4 acc[4][4] = {};

    const int wm   = (wave >> 1) * 64;
    const int wn   = (wave & 1) * 64;
    const int fRow = lane & 15;
    const int fK   = (lane >> 4) * 8;

    // A: 8 fp32x4 loads (rows sRow, sRow+64; k-chunks kt, kt+BK; 8 elems each)
    auto A_LOAD = [&](int kt, floatx4* r) {
        const float* p0 = Ag + kt;                    // row sRow
        const float* p1 = Ag + kt + (size_t)64 * K;   // row sRow+64
        r[0] = *(const floatx4*)(p0);        r[1] = *(const floatx4*)(p0 + 4);
        r[2] = *(const floatx4*)(p0 + BK);   r[3] = *(const floatx4*)(p0 + BK + 4);
        r[4] = *(const floatx4*)(p1);        r[5] = *(const floatx4*)(p1 + 4);
        r[6] = *(const floatx4*)(p1 + BK);   r[7] = *(const floatx4*)(p1 + BK + 4);
    };
    auto A_WRITE = [&](int buf, const floatx4* r) {   // pack8 (RNE) + ds_write
        unsigned short* Al = &As[buf][ldsOff];
        *(shortx8*)(Al)                    = pack8(r[0], r[1]);  // chunk0, row
        *(shortx8*)(Al + BM * BK)          = pack8(r[2], r[3]);  // chunk1, row
        *(shortx8*)(Al + 64 * BK)          = pack8(r[4], r[5]);  // chunk0, row+64
        *(shortx8*)(Al + BM * BK + 64*BK)  = pack8(r[6], r[7]);  // chunk1, row+64
    };
    auto B_STAGE = [&](int kt, int buf) {             // 4 global_load_lds
        unsigned short* Bl = &Bs[buf][ldsOff];
        ld16(Bg + kt,                      Bl);
        ld16(Bg + kt + (size_t)64 * K,     Bl + 64 * BK);
        ld16(Bg + kt + BK,                 Bl + BN * BK);
        ld16(Bg + kt + BK + (size_t)64*K,  Bl + BN * BK + 64 * BK);
    };
    auto COMPUTE = [&](int buf) {                     // 16 ds_read + 32 MFMA
        const unsigned short* Ab = As[buf];
        const unsigned short* Bb = Bs[buf];
        #pragma unroll
        for (int c = 0; c < 2; c++) {
            const unsigned short* Asc = Ab + c * BM * BK;
            const unsigned short* Bsc = Bb + c * BN * BK;
            shortx8 af[4], bfr[4];
            #pragma unroll
            for (int i = 0; i < 4; i++) {
                af[i]  = *(const shortx8*)&Asc[(wm + i*16 + fRow) * BK + fK];
                bfr[i] = *(const shortx8*)&Bsc[(wn + i*16 + fRow) * BK + fK];
            }
            #pragma unroll
            for (int i = 0; i < 4; i++)
                #pragma unroll
                for (int j = 0; j < 4; j++)
                    acc[i][j] = __builtin_amdgcn_mfma_f32_16x16x32_bf16(
                        af[i], bfr[j], acc[i][j], 0, 0, 0);
        }
    };

    const int NT = K / (2 * BK);                      // 12 tiles of 64
    floatx4 ar[8];

    // ---- prologue: tile 0 ----
    A_LOAD(0, ar);
    B_STAGE(0, 0);
    A_WRITE(0, ar);
    __syncthreads();          // drains vmcnt (B) + lgkm (A writes)

    for (int t = 0; t < NT; ++t) {
        if (t + 1 < NT) {
            A_LOAD((t + 1) * 2 * BK, ar);    // fp32 loads issued EARLY
            B_STAGE((t + 1) * 2 * BK, (t + 1) & 1);
        }
        COMPUTE(t & 1);                      // hides the loads above
        if (t + 1 < NT) A_WRITE((t + 1) & 1, ar);  // pack lands post-compute
        __syncthreads();
    }

    // C/D layout: col = lane&15, row = (lane>>4)*4 + reg
    const int cRow = (lane >> 4) * 4;
    const int cCol = lane & 15;
    unsigned short* Out = (z == 0) ? Qb16 : ((z == 1) ? Kb : Vb);
    #pragma unroll
    for (int j = 0; j < 4; j++) {
        const int col = nBlock + wn + j*16 + cCol;
        const float bvf = bias[col];
        #pragma unroll
        for (int i = 0; i < 4; i++)
            #pragma unroll
            for (int r = 0; r < 4; r++)
                Out[(size_t)(mBlock + wm + i*16 + cRow + r) * N + col] =
                    f2bf(acc[i][j][r] + bvf);
    }
}

// ---------- fallback GEMM (proven): fp32 src, pack in kernel ----------
__global__ __launch_bounds__(256) void gemm_qkv_f32(
    const float* __restrict__ X,
    const float* __restrict__ Wq, const float* __restrict__ Wk,
    const float* __restrict__ Wv,
    const float* __restrict__ bq, const float* __restrict__ bk,
    const float* __restrict__ bv,
    float* __restrict__ Qf, unsigned short* __restrict__ Kb,
    unsigned short* __restrict__ Vb,
    int M, int N, int K)
{
    __shared__ __attribute__((aligned(16))) unsigned short As[BM * BK];
    __shared__ __attribute__((aligned(16))) unsigned short Bs[BN * BK];

    const float* W;  const float* bias;
    if (blockIdx.z == 0)      { W = Wq; bias = bq; }
    else if (blockIdx.z == 1) { W = Wk; bias = bk; }
    else                      { W = Wv; bias = bv; }

    const int tid  = threadIdx.x;
    const int wave = tid >> 6;
    const int lane = tid & 63;
    const int mBlock = blockIdx.y * BM;
    const int nBlock = blockIdx.x * BN;

    const int sRow = tid >> 1;
    const int sCol = (tid & 1) * 16;
    const float* Ag = X + (size_t)(mBlock + sRow) * K + sCol;
    const float* Bg = W + (size_t)(nBlock + sRow) * K + sCol;
    unsigned short* Al = &As[sRow * BK + sCol];
    unsigned short* Bl = &Bs[sRow * BK + sCol];

    floatx4 acc[4][4] = {};
    const int wm   = (wave >> 1) * 64;
    const int wn   = (wave & 1) * 64;
    const int fRow = lane & 15;
    const int fK   = (lane >> 4) * 8;

    for (int kt = 0; kt < K; kt += BK) {
        floatx4 a[4], b[4];
        #pragma unroll
        for (int c = 0; c < 4; c++) {
            a[c] = *(const floatx4*)(Ag + kt + c * 4);
            b[c] = *(const floatx4*)(Bg + kt + c * 4);
        }
        __syncthreads();
        *(shortx8*)(Al)     = pack8(a[0], a[1]);
        *(shortx8*)(Al + 8) = pack8(a[2], a[3]);
        *(shortx8*)(Bl)     = pack8(b[0], b[1]);
        *(shortx8*)(Bl + 8) = pack8(b[2], b[3]);
        __syncthreads();

        shortx8 af[4], bfr[4];
        #pragma unroll
        for (int i = 0; i < 4; i++) {
            af[i]  = *(const shortx8*)&As[(wm + i*16 + fRow) * BK + fK];
            bfr[i] = *(const shortx8*)&Bs[(wn + i*16 + fRow) * BK + fK];
        }
        #pragma unroll
        for (int i = 0; i < 4; i++)
            #pragma unroll
            for (int j = 0; j < 4; j++)
                acc[i][j] = __builtin_amdgcn_mfma_f32_16x16x32_bf16(
                    af[i], bfr[j], acc[i][j], 0, 0, 0);
    }

    const int cRow = (lane >> 4) * 4;
    const int cCol = lane & 15;
    if (blockIdx.z == 0) {
        #pragma unroll
        for (int j = 0; j < 4; j++) {
            const int col = nBlock + wn + j*16 + cCol;
            const float bvf = bias[col];
            #pragma unroll
            for (int i = 0; i < 4; i++)
                #pragma unroll
                for (int r = 0; r < 4; r++)
                    Qf[(size_t)(mBlock + wm + i*16 + cRow + r) * N + col] =
                        acc[i][j][r] + bvf;
        }
    } else {
        unsigned short* Out = (blockIdx.z == 1) ? Kb : Vb;
        #pragma unroll
        for (int j = 0; j < 4; j++) {
            const int col = nBlock + wn + j*16 + cCol;
            const float bvf = bias[col];
            #pragma unroll
            for (int i = 0; i < 4; i++)
                #pragma unroll
                for (int r = 0; r < 4; r++)
                    Out[(size_t)(mBlock + wm + i*16 + cRow + r) * N + col] =
                        f2bf(acc[i][j][r] + bvf);
        }
    }
}

// ---------- sampler v2b: 4 waves/block, b walked DESCENDING per XCD ----------
__global__ __launch_bounds__(256) void sample_attend(
    const float* __restrict__ Qf,            // fp32 q (if Qb16 == null)
    const unsigned short* __restrict__ Qb16, // bf16 q (preferred)
    const unsigned short* __restrict__ Kb,
    const unsigned short* __restrict__ Vb,
    const float* __restrict__ normx,
    const float* __restrict__ normy,
    const int* __restrict__ img_ids,
    const float* __restrict__ avgs,
    const float* __restrict__ stds,
    float* __restrict__ out)
{
    const unsigned g    = blockIdx.x;            // 0..6271
    const unsigned xcd  = g & 7;
    const unsigned slot = g >> 3;                // 0..783
    const int b = (int)(xcd * 16 + (15 - slot / 49));
    const int p = (int)((slot % 49) * 4 + (threadIdx.x >> 6));
    const int lane = threadIdx.x & 63;

    const size_t rowOff = ((size_t)b * 196 + p) * 768;
    const int d0 = lane * 8;                     // elems [d0, d0+8)
    const int d1 = 512 + lane * 4;               // elems [d1, d1+4)

    // ---- issue q loads first (independent of coord computation) ----
    float q[12];
    if (Qb16 != nullptr) {
        const shortx8 q16 = *(const shortx8*)&Qb16[rowOff + d0];
        const unsigned long long q8 = *(const unsigned long long*)&Qb16[rowOff + d1];
        #pragma unroll
        for (int e = 0; e < 8; e++) q[e] = bf2f((unsigned short)q16[e]);
        #pragma unroll
        for (int e = 0; e < 4; e++) q[8 + e] = bf2f((unsigned short)(q8 >> (16 * e)));
    } else {
        const floatx4 qa = *(const floatx4*)&Qf[rowOff + d0];
        const floatx4 qb2 = *(const floatx4*)&Qf[rowOff + d0 + 4];
        const floatx4 qc = *(const floatx4*)&Qf[rowOff + d1];
        #pragma unroll
        for (int e = 0; e < 4; e++) { q[e] = qa[e]; q[4 + e] = qb2[e]; q[8 + e] = qc[e]; }
    }

    const int id = img_ids[b];
    // grid flat = [sx(196), sy(196)]: gx = flat[2p], gy = flat[2p+1]
    auto coord = [&](int n) -> float {
        int c = 0;
        if (n >= 196) { n -= 196; c = 1; }
        const float base = (c == 0) ? normx[b * 196 + n] : normy[b * 196 + n];
        const float a = avgs[(size_t)id * 392 + c * 196 + n];
        const float s = stds[(size_t)id * 392 + c * 196 + n];
        return tanhf((base + a) * s);
    };
    const float gx = coord(2 * p);
    const float gy = coord(2 * p + 1);

    const float ix = ((gx + 1.0f) * 14.0f - 1.0f) * 0.5f;
    const float iy = ((gy + 1.0f) * 14.0f - 1.0f) * 0.5f;
    const float x0f = floorf(ix), y0f = floorf(iy);
    const float wx1 = ix - x0f, wx0 = 1.0f - wx1;
    const float wy1 = iy - y0f, wy0 = 1.0f - wy1;
    const int x0 = (int)x0f, y0 = (int)y0f;

    float cw[4]; int rr[4];
    {
        const int xs[4] = {x0, x0 + 1, x0, x0 + 1};
        const int ys[4] = {y0, y0, y0 + 1, y0 + 1};
        const float ws4[4] = {wx0 * wy0, wx1 * wy0, wx0 * wy1, wx1 * wy1};
        #pragma unroll
        for (int c = 0; c < 4; c++) {
            const bool valid = xs[c] >= 0 && xs[c] <= 13 && ys[c] >= 0 && ys[c] <= 13;
            cw[c] = valid ? ws4[c] : 0.0f;
            rr[c] = valid ? (ys[c] * 14 + xs[c]) * 768 : 0;
        }
    }

    const unsigned short* kb = Kb + (size_t)b * 196 * 768;
    const unsigned short* vb = Vb + (size_t)b * 196 * 768;

    // ---- gather all corner streams (independent loads, MLP-friendly) ----
    shortx8 k16[4], v16[4];
    unsigned long long k8[4], v8[4];
    #pragma unroll
    for (int c = 0; c < 4; c++) {
        k16[c] = *(const shortx8*)&kb[rr[c] + d0];
        v16[c] = *(const shortx8*)&vb[rr[c] + d0];
        k8[c]  = *(const unsigned long long*)&kb[rr[c] + d1];
        v8[c]  = *(const unsigned long long*)&vb[rr[c] + d1];
    }

    float kx[12] = {}, vx[12] = {};
    #pragma unroll
    for (int c = 0; c < 4; c++) {
        #pragma unroll
        for (int e = 0; e < 8; e++) {
            kx[e] += cw[c] * bf2f((unsigned short)k16[c][e]);
            vx[e] += cw[c] * bf2f((unsigned short)v16[c][e]);
        }
        #pragma unroll
        for (int e = 0; e < 4; e++) {
            kx[8 + e] += cw[c] * bf2f((unsigned short)(k8[c] >> (16 * e)));
            vx[8 + e] += cw[c] * bf2f((unsigned short)(v8[c] >> (16 * e)));
        }
    }

    float partial = 0.0f;
    #pragma unroll
    for (int e = 0; e < 12; e++) partial += kx[e] * q[e];

    #pragma unroll
    for (int off = 32; off >= 1; off >>= 1)
        partial += __shfl_xor(partial, off, 64);
    const float sig = 1.0f / (1.0f + expf(-0.01f * partial));

    floatx4 o0, o1, o2;
    #pragma unroll
    for (int e = 0; e < 4; e++) {
        o0[e] = sig * vx[e];
        o1[e] = sig * vx[4 + e];
        o2[e] = sig * vx[8 + e];
    }
    *(floatx4*)&out[rowOff + d0]     = o0;
    *(floatx4*)&out[rowOff + d0 + 4] = o1;
    *(floatx4*)&out[rowOff + d1]     = o2;
}

extern "C" void kernel_launch(void* const* d_in, const int* in_sizes, int n_in,
                              void* d_out, int out_size, void* d_ws, size_t ws_size,
                              hipStream_t stream) {
    const float* x     = (const float*)d_in[0];
    const int*   ids   = (const int*)d_in[1];
    // d_in[2] = mask (unused by reference)
    const float* normx = (const float*)d_in[3];
    const float* normy = (const float*)d_in[4];
    const float* Wq    = (const float*)d_in[5];
    const float* bq    = (const float*)d_in[6];
    const float* Wk    = (const float*)d_in[7];
    const float* bk    = (const float*)d_in[8];
    const float* Wv    = (const float*)d_in[9];
    const float* bv    = (const float*)d_in[10];
    const float* avgs  = (const float*)d_in[11];
    const float* stds  = (const float*)d_in[12];
    float* out = (float*)d_out;

    const int B = 128, P = 196, D = 768;
    const int M = B * P;                         // 25088
    const size_t qkvElems = (size_t)M * D;       // 19,267,584
    const size_t wElems   = (size_t)D * D;       // 589,824

    // ws: Wb(3) + k + v + qb, all bf16 (Xb no longer needed: A converts
    // in-kernel) = (3*wElems + 3*qkvElems)*2 bytes (~119 MB)
    const size_t need = (3 * qkvElems + 3 * wElems) * 2;

    const int nSampBlocks = 8 * 16 * 49;         // 6272 (4 p per block)

    if (ws_size >= need) {
        unsigned short* Wb = (unsigned short*)d_ws;
        unsigned short* k  = Wb + 3 * wElems;
        unsigned short* v  = k + qkvElems;
        unsigned short* qb = v + qkvElems;

        // W-only convert: 3 x 288 = 864 blocks (4th segment unreachable)
        const int nbW = (int)(wElems / 8 / 256);     // 288
        cvt4<<<3 * nbW, 256, 0, stream>>>(
            Wq, Wk, Wv, Wv, Wb, Wb + wElems, Wb + 2 * wElems, Wb + 2 * wElems,
            nbW, nbW, nbW);

        const int nGemmBlocks = (D / BN) * (M / BM) * 3;   // 3528 = 8*441
        gemm_qkv_bf16<<<nGemmBlocks, 256, 0, stream>>>(
            x, Wb, bq, bk, bv, qb, k, v, M, D, D);

        sample_attend<<<nSampBlocks, 256, 0, stream>>>(
            nullptr, qb, k, v, normx, normy, ids, avgs, stds, out);
    } else {
        unsigned short* k = (unsigned short*)d_ws;
        unsigned short* v = k + qkvElems;

        dim3 gGemm(D / BN, M / BM, 3);
        gemm_qkv_f32<<<gGemm, 256, 0, stream>>>(
            x, Wq, Wk, Wv, bq, bk, bv, out, k, v, M, D, D);

        sample_attend<<<nSampBlocks, 256, 0, stream>>>(
            out, nullptr, k, v, normx, normy, ids, avgs, stds, out);
    }
}

// Round 8
// 313.163 us; speedup vs baseline: 1.1522x; 1.1522x over previous
//
#include <hip/hip_runtime.h>
#include <hip/hip_bf16.h>

typedef __attribute__((ext_vector_type(4))) float floatx4;
typedef __attribute__((ext_vector_type(8))) short shortx8;
typedef __attribute__((address_space(3))) void as3_void;
typedef const __attribute__((address_space(1))) void as1_void;

__device__ __forceinline__ unsigned short f2bf(float f) {
    unsigned int u; __builtin_memcpy(&u, &f, 4);
    u += 0x7FFFu + ((u >> 16) & 1u);   // RNE
    return (unsigned short)(u >> 16);
}
__device__ __forceinline__ float bf2f(unsigned short h) {
    unsigned int u = ((unsigned int)h) << 16;
    float f; __builtin_memcpy(&f, &u, 4); return f;
}
__device__ __forceinline__ shortx8 pack8(floatx4 lo, floatx4 hi) {
    shortx8 r;
    r[0] = (short)f2bf(lo[0]); r[1] = (short)f2bf(lo[1]);
    r[2] = (short)f2bf(lo[2]); r[3] = (short)f2bf(lo[3]);
    r[4] = (short)f2bf(hi[0]); r[5] = (short)f2bf(hi[1]);
    r[6] = (short)f2bf(hi[2]); r[7] = (short)f2bf(hi[3]);
    return r;
}
__device__ __forceinline__ void ld16(const unsigned short* g, unsigned short* l) {
    __builtin_amdgcn_global_load_lds((as1_void*)g, (as3_void*)l, 16, 0, 0);
}

#define MFMA1(d, a, b) d = __builtin_amdgcn_mfma_f32_16x16x32_bf16(a, b, d, 0, 0, 0)
#define BARm asm volatile("s_barrier" ::: "memory")

// ---------- fp32 -> bf16 pre-convert (4 segments in one launch) ----------
__global__ __launch_bounds__(256) void cvt4(
    const float* __restrict__ s0, const float* __restrict__ s1,
    const float* __restrict__ s2, const float* __restrict__ s3,
    unsigned short* __restrict__ d0, unsigned short* __restrict__ d1,
    unsigned short* __restrict__ d2, unsigned short* __restrict__ d3,
    int nb0, int nb1, int nb2)
{
    int bid = blockIdx.x;
    const float* s; unsigned short* d;
    if (bid < nb0)                  { s = s0; d = d0; }
    else if (bid < nb0 + nb1)       { s = s1; d = d1; bid -= nb0; }
    else if (bid < nb0 + nb1 + nb2) { s = s2; d = d2; bid -= nb0 + nb1; }
    else                            { s = s3; d = d3; bid -= nb0 + nb1 + nb2; }
    const size_t i = ((size_t)bid * 256 + threadIdx.x) * 8;
    const floatx4 lo = *(const floatx4*)(s + i);
    const floatx4 hi = *(const floatx4*)(s + i + 4);
    *(shortx8*)(d + i) = pack8(lo, hi);
}

// ---------- GEMM v7: faithful 256x256 8-phase (T1+T2+T3+T4+T5) ----------
// C[25088 x 2304] = Xb * Wb^T (N folded over q/k/v), K=768 -> 12 K-tiles of
// 64, 6 iterations x 8 phases. 8 waves (2M x 4N), per-wave 128x64 out.
// LDS 128 KiB: As/Bs[2 dbuf][2 half][128x64] (static tile->dbuf: even->0).
// Per phase: {ds_read subtile; stage ONE half-tile (2 ld16); s_barrier;
// MFMA quadrant (16); s_barrier}. Quadrant order (ih0,n01)->(ih0,n23)->
// (ih1,n23)->(ih1,n01): B last read ph1, A last read ph2 -> regions free
// early, stages land 3-7 phases before use. Counted vmcnt(4) only at ph3/ph7
// ends (2 newest half-tiles allowed outstanding) - never drain mid-loop.
// Barriers are raw s_barrier asm + "memory" clobber (compiler fence, NO
// forced vmcnt(0) like __syncthreads). ds_reads are plain C++ (compiler owns
// lgkm waits -> rule-18 safe). Swizzle = round-2's proven 0-conflict
// chunk-XOR (slot = chunk ^ (row&7)), staged via pre-swizzled global col.
// Stage mapping per iteration j (tiles T0=2j db0 ph0-3, T1=2j+1 db1 ph4-7):
//   ph0: A(2j+1,h0)  ph1: A(2j+1,h1)   [WAR: A(2j-1) last read iter j-1 ph6]
//   ph2: B(2j+2,h0)  ph3: B(2j+2,h1)   [WAR: B(2j)   last read ph1]
//   ph4: A(2j+2,h0)  ph5: A(2j+2,h1)   [WAR: A(2j)   last read ph2]
//   ph6: B(2j+3,h0)  ph7: B(2j+3,h1)   [WAR: B(2j+1) last read ph5]
// RAW: ph3-end vmcnt(4) leaves only B(2j+2) outstanding -> A(2j+1) landed
// before ph4; ph7-end vmcnt(4) leaves only B(2j+3) -> tile 2j+2 landed.
// Tail j=5: stages of tiles>=12 skipped; ph3-end uses vmcnt(0) (A(11) would
// be the only outstanding loads -> counted wait can't see them).
__global__ __launch_bounds__(512, 2) void gemm_qkv_8ph(
    const unsigned short* __restrict__ Xb,
    const unsigned short* __restrict__ Wb,   // 3 contiguous 768x768 = 2304x768
    const float* __restrict__ bq, const float* __restrict__ bk,
    const float* __restrict__ bv,
    float* __restrict__ Qf, unsigned short* __restrict__ Qb16,
    unsigned short* __restrict__ Kb, unsigned short* __restrict__ Vb)
{
    __shared__ __attribute__((aligned(16))) unsigned short As[2][2][8192];
    __shared__ __attribute__((aligned(16))) unsigned short Bs[2][2][8192];

    // bijective XCD swizzle for 882 blocks (q=110, r=2), y-grouped: the 9
    // n-tiles sharing an A-panel land on one XCD (round-2 FETCH: 80 MB).
    const unsigned orig = blockIdx.x;
    const unsigned xcd = orig & 7u, loc = orig >> 3;
    const unsigned wg = (xcd < 2u ? xcd * 111u : 222u + (xcd - 2u) * 110u) + loc;
    const unsigned yb = wg / 9u;
    const unsigned nb = wg - yb * 9u;

    const int tid  = threadIdx.x;
    const int wave = tid >> 6, lane = tid & 63;
    const int fRow = lane & 15, gq = lane >> 4;
    const int wm2  = wave >> 2;            // A half (0/1)
    const int wn4  = wave & 3;
    const int hB   = wn4 >> 1;             // B half
    const int bRow0 = (wn4 & 1) * 64;      // row offset within B half
    const int mBlock = (int)yb * 256;
    const int nRow0  = (int)nb * 256;      // folded B row base

    // staging: thread t -> row (t>>3) (+64 for 2nd load), LDS slot t&7;
    // global col chunk = (t&7) ^ (row&7)  [swizzle involution, linear dest]
    const int srow0 = tid >> 3;
    const int scol  = ((tid & 7) ^ (srow0 & 7)) * 8;
    const int dOff  = tid * 8;

    auto stA = [&](int t, int h, int db) {
        const unsigned short* s =
            Xb + (size_t)(mBlock + h * 128 + srow0) * 768 + t * 64 + scol;
        unsigned short* d = &As[db][h][dOff];
        ld16(s, d);
        ld16(s + (size_t)64 * 768, d + 4096);
    };
    auto stB = [&](int t, int h, int db) {
        const unsigned short* s =
            Wb + (size_t)(nRow0 + h * 128 + srow0) * 768 + t * 64 + scol;
        unsigned short* d = &Bs[db][h][dOff];
        ld16(s, d);
        ld16(s + (size_t)64 * 768, d + 4096);
    };

    // read col (swizzled): want global chunk s*4+gq at row r (r&7 == fRow&7)
    const int rc0 = ((0 + gq) ^ (fRow & 7)) * 8;
    const int rc1 = ((4 + gq) ^ (fRow & 7)) * 8;

    floatx4 acc[8][4] = {};

    auto TILE = [&](int db, auto S0, auto S1, auto S2, auto S3, int ck) {
        shortx8 aF[4][2], bF[4][2];
        const unsigned short* Ah = As[db][wm2];
        const unsigned short* Bh = Bs[db][hB];
        // ---- q0: read A(ih0) 8 + B(n0,n1) 4; stage S0; MFMA (ih0, n0-1)
        #pragma unroll
        for (int ii = 0; ii < 4; ++ii) {
            const int rb = (ii * 16 + fRow) * 64;
            aF[ii][0] = *(const shortx8*)&Ah[rb + rc0];
            aF[ii][1] = *(const shortx8*)&Ah[rb + rc1];
        }
        #pragma unroll
        for (int nn = 0; nn < 2; ++nn) {
            const int rb = (bRow0 + nn * 16 + fRow) * 64;
            bF[nn][0] = *(const shortx8*)&Bh[rb + rc0];
            bF[nn][1] = *(const shortx8*)&Bh[rb + rc1];
        }
        S0();
        BARm;
        __builtin_amdgcn_s_setprio(1);
        #pragma unroll
        for (int ii = 0; ii < 4; ++ii)
            #pragma unroll
            for (int nn = 0; nn < 2; ++nn) {
                MFMA1(acc[ii][nn], aF[ii][0], bF[nn][0]);
                MFMA1(acc[ii][nn], aF[ii][1], bF[nn][1]);
            }
        __builtin_amdgcn_s_setprio(0);
        BARm;
        // ---- q1: read B(n2,n3) 4; stage S1; MFMA (ih0, n2-3)
        #pragma unroll
        for (int nn = 2; nn < 4; ++nn) {
            const int rb = (bRow0 + nn * 16 + fRow) * 64;
            bF[nn][0] = *(const shortx8*)&Bh[rb + rc0];
            bF[nn][1] = *(const shortx8*)&Bh[rb + rc1];
        }
        S1();
        BARm;
        __builtin_amdgcn_s_setprio(1);
        #pragma unroll
        for (int ii = 0; ii < 4; ++ii)
            #pragma unroll
            for (int nn = 2; nn < 4; ++nn) {
                MFMA1(acc[ii][nn], aF[ii][0], bF[nn][0]);
                MFMA1(acc[ii][nn], aF[ii][1], bF[nn][1]);
            }
        __builtin_amdgcn_s_setprio(0);
        BARm;
        // ---- q2: read A(ih1) 8 (reuse aF); stage S2; MFMA (ih1, n2-3)
        #pragma unroll
        for (int ii = 0; ii < 4; ++ii) {
            const int rb = ((ii + 4) * 16 + fRow) * 64;
            aF[ii][0] = *(const shortx8*)&Ah[rb + rc0];
            aF[ii][1] = *(const shortx8*)&Ah[rb + rc1];
        }
        S2();
        BARm;
        __builtin_amdgcn_s_setprio(1);
        #pragma unroll
        for (int ii = 0; ii < 4; ++ii)
            #pragma unroll
            for (int nn = 2; nn < 4; ++nn) {
                MFMA1(acc[4 + ii][nn], aF[ii][0], bF[nn][0]);
                MFMA1(acc[4 + ii][nn], aF[ii][1], bF[nn][1]);
            }
        __builtin_amdgcn_s_setprio(0);
        BARm;
        // ---- q3: stage S3; MFMA (ih1, n0-1); checkpoint; barrier
        S3();
        BARm;
        __builtin_amdgcn_s_setprio(1);
        #pragma unroll
        for (int ii = 0; ii < 4; ++ii)
            #pragma unroll
            for (int nn = 0; nn < 2; ++nn) {
                MFMA1(acc[4 + ii][nn], aF[ii][0], bF[nn][0]);
                MFMA1(acc[4 + ii][nn], aF[ii][1], bF[nn][1]);
            }
        __builtin_amdgcn_s_setprio(0);
        if (ck == 4)      { asm volatile("s_waitcnt vmcnt(4)" ::: "memory"); }
        else if (ck == 0) { asm volatile("s_waitcnt vmcnt(0)" ::: "memory"); }
        BARm;
    };

    // ---- prologue: tile 0 (4 halves) then B(1) (2 halves); wait tile 0 ----
    stA(0, 0, 0); stA(0, 1, 0); stB(0, 0, 0); stB(0, 1, 0);
    asm volatile("" ::: "memory");          // keep issue order for vmcnt math
    stB(1, 0, 1); stB(1, 1, 1);
    asm volatile("s_waitcnt vmcnt(4)" ::: "memory");
    BARm;

    for (int j = 0; j < 6; ++j) {
        const int t1 = 2 * j + 1, t2 = 2 * j + 2, t3 = 2 * j + 3;
        TILE(0,
             [&] { stA(t1, 0, 1); },
             [&] { stA(t1, 1, 1); },
             [&] { if (t2 < 12) stB(t2, 0, 0); },
             [&] { if (t2 < 12) stB(t2, 1, 0); },
             (j < 5) ? 4 : 0);
        TILE(1,
             [&] { if (t2 < 12) stA(t2, 0, 0); },
             [&] { if (t2 < 12) stA(t2, 1, 0); },
             [&] { if (t3 < 12) stB(t3, 0, 1); },
             [&] { if (t3 < 12) stB(t3, 1, 1); },
             (j < 5) ? 4 : -1);
    }

    // ---- epilogue: C/D col = lane&15, row = (lane>>4)*4 + reg ----
    const int z = (int)nb / 3;
    const int colBase = ((int)nb - z * 3) * 256 + wn4 * 64;
    const float* bias = (z == 0) ? bq : ((z == 1) ? bk : bv);
    const int rowBase = mBlock + wm2 * 128;
    if (z == 0 && Qb16 == nullptr) {
        #pragma unroll
        for (int n = 0; n < 4; ++n) {
            const int col = colBase + n * 16 + fRow;
            const float bvf = bias[col];
            #pragma unroll
            for (int i = 0; i < 8; ++i)
                #pragma unroll
                for (int r = 0; r < 4; ++r)
                    Qf[(size_t)(rowBase + i * 16 + gq * 4 + r) * 768 + col] =
                        acc[i][n][r] + bvf;
        }
    } else {
        unsigned short* Out = (z == 0) ? Qb16 : ((z == 1) ? Kb : Vb);
        float bvf[4];
        #pragma unroll
        for (int n = 0; n < 4; ++n) bvf[n] = bias[colBase + n * 16 + fRow];
        // n-pair innermost: both 32-B halves of a 64-B line written
        // back-to-back per row (round-2 write-amp fix, 210 -> ~114 MB).
        #pragma unroll
        for (int np = 0; np < 2; ++np)
            #pragma unroll
            for (int i = 0; i < 8; ++i)
                #pragma unroll
                for (int r = 0; r < 4; ++r) {
                    const size_t ro = (size_t)(rowBase + i * 16 + gq * 4 + r) * 768;
                    #pragma unroll
                    for (int n = 2 * np; n < 2 * np + 2; ++n)
                        Out[ro + colBase + n * 16 + fRow] =
                            f2bf(acc[i][n][r] + bvf[n]);
                }
    }
}

#define BM 128
#define BN 128
#define BK 32

// ---------- fallback GEMM (proven): fp32 src, pack in kernel ----------
__global__ __launch_bounds__(256) void gemm_qkv_f32(
    const float* __restrict__ X,
    const float* __restrict__ Wq, const float* __restrict__ Wk,
    const float* __restrict__ Wv,
    const float* __restrict__ bq, const float* __restrict__ bk,
    const float* __restrict__ bv,
    float* __restrict__ Qf, unsigned short* __restrict__ Kb,
    unsigned short* __restrict__ Vb,
    int M, int N, int K)
{
    __shared__ __attribute__((aligned(16))) unsigned short As[BM * BK];
    __shared__ __attribute__((aligned(16))) unsigned short Bs[BN * BK];

    const float* W;  const float* bias;
    if (blockIdx.z == 0)      { W = Wq; bias = bq; }
    else if (blockIdx.z == 1) { W = Wk; bias = bk; }
    else                      { W = Wv; bias = bv; }

    const int tid  = threadIdx.x;
    const int wave = tid >> 6;
    const int lane = tid & 63;
    const int mBlock = blockIdx.y * BM;
    const int nBlock = blockIdx.x * BN;

    const int sRow = tid >> 1;
    const int sCol = (tid & 1) * 16;
    const float* Ag = X + (size_t)(mBlock + sRow) * K + sCol;
    const float* Bg = W + (size_t)(nBlock + sRow) * K + sCol;
    unsigned short* Al = &As[sRow * BK + sCol];
    unsigned short* Bl = &Bs[sRow * BK + sCol];

    floatx4 acc[4][4] = {};
    const int wm   = (wave >> 1) * 64;
    const int wn   = (wave & 1) * 64;
    const int fRow = lane & 15;
    const int fK   = (lane >> 4) * 8;

    for (int kt = 0; kt < K; kt += BK) {
        floatx4 a[4], b[4];
        #pragma unroll
        for (int c = 0; c < 4; c++) {
            a[c] = *(const floatx4*)(Ag + kt + c * 4);
            b[c] = *(const floatx4*)(Bg + kt + c * 4);
        }
        __syncthreads();
        *(shortx8*)(Al)     = pack8(a[0], a[1]);
        *(shortx8*)(Al + 8) = pack8(a[2], a[3]);
        *(shortx8*)(Bl)     = pack8(b[0], b[1]);
        *(shortx8*)(Bl + 8) = pack8(b[2], b[3]);
        __syncthreads();

        shortx8 af[4], bfr[4];
        #pragma unroll
        for (int i = 0; i < 4; i++) {
            af[i]  = *(const shortx8*)&As[(wm + i*16 + fRow) * BK + fK];
            bfr[i] = *(const shortx8*)&Bs[(wn + i*16 + fRow) * BK + fK];
        }
        #pragma unroll
        for (int i = 0; i < 4; i++)
            #pragma unroll
            for (int j = 0; j < 4; j++)
                acc[i][j] = __builtin_amdgcn_mfma_f32_16x16x32_bf16(
                    af[i], bfr[j], acc[i][j], 0, 0, 0);
    }

    const int cRow = (lane >> 4) * 4;
    const int cCol = lane & 15;
    if (blockIdx.z == 0) {
        #pragma unroll
        for (int j = 0; j < 4; j++) {
            const int col = nBlock + wn + j*16 + cCol;
            const float bvf = bias[col];
            #pragma unroll
            for (int i = 0; i < 4; i++)
                #pragma unroll
                for (int r = 0; r < 4; r++)
                    Qf[(size_t)(mBlock + wm + i*16 + cRow + r) * N + col] =
                        acc[i][j][r] + bvf;
        }
    } else {
        unsigned short* Out = (blockIdx.z == 1) ? Kb : Vb;
        #pragma unroll
        for (int j = 0; j < 4; j++) {
            const int col = nBlock + wn + j*16 + cCol;
            const float bvf = bias[col];
            #pragma unroll
            for (int i = 0; i < 4; i++)
                #pragma unroll
                for (int r = 0; r < 4; r++)
                    Out[(size_t)(mBlock + wm + i*16 + cRow + r) * N + col] =
                        f2bf(acc[i][j][r] + bvf);
        }
    }
}

// ---------- sampler v2b: 4 waves/block, b walked DESCENDING per XCD ----------
__global__ __launch_bounds__(256) void sample_attend(
    const float* __restrict__ Qf,            // fp32 q (if Qb16 == null)
    const unsigned short* __restrict__ Qb16, // bf16 q (preferred)
    const unsigned short* __restrict__ Kb,
    const unsigned short* __restrict__ Vb,
    const float* __restrict__ normx,
    const float* __restrict__ normy,
    const int* __restrict__ img_ids,
    const float* __restrict__ avgs,
    const float* __restrict__ stds,
    float* __restrict__ out)
{
    const unsigned g    = blockIdx.x;            // 0..6271
    const unsigned xcd  = g & 7;
    const unsigned slot = g >> 3;                // 0..783
    const int b = (int)(xcd * 16 + (15 - slot / 49));
    const int p = (int)((slot % 49) * 4 + (threadIdx.x >> 6));
    const int lane = threadIdx.x & 63;

    const size_t rowOff = ((size_t)b * 196 + p) * 768;
    const int d0 = lane * 8;                     // elems [d0, d0+8)
    const int d1 = 512 + lane * 4;               // elems [d1, d1+4)

    float q[12];
    if (Qb16 != nullptr) {
        const shortx8 q16 = *(const shortx8*)&Qb16[rowOff + d0];
        const unsigned long long q8 = *(const unsigned long long*)&Qb16[rowOff + d1];
        #pragma unroll
        for (int e = 0; e < 8; e++) q[e] = bf2f((unsigned short)q16[e]);
        #pragma unroll
        for (int e = 0; e < 4; e++) q[8 + e] = bf2f((unsigned short)(q8 >> (16 * e)));
    } else {
        const floatx4 qa = *(const floatx4*)&Qf[rowOff + d0];
        const floatx4 qb2 = *(const floatx4*)&Qf[rowOff + d0 + 4];
        const floatx4 qc = *(const floatx4*)&Qf[rowOff + d1];
        #pragma unroll
        for (int e = 0; e < 4; e++) { q[e] = qa[e]; q[4 + e] = qb2[e]; q[8 + e] = qc[e]; }
    }

    const int id = img_ids[b];
    auto coord = [&](int n) -> float {
        int c = 0;
        if (n >= 196) { n -= 196; c = 1; }
        const float base = (c == 0) ? normx[b * 196 + n] : normy[b * 196 + n];
        const float a = avgs[(size_t)id * 392 + c * 196 + n];
        const float s = stds[(size_t)id * 392 + c * 196 + n];
        return tanhf((base + a) * s);
    };
    const float gx = coord(2 * p);
    const float gy = coord(2 * p + 1);

    const float ix = ((gx + 1.0f) * 14.0f - 1.0f) * 0.5f;
    const float iy = ((gy + 1.0f) * 14.0f - 1.0f) * 0.5f;
    const float x0f = floorf(ix), y0f = floorf(iy);
    const float wx1 = ix - x0f, wx0 = 1.0f - wx1;
    const float wy1 = iy - y0f, wy0 = 1.0f - wy1;
    const int x0 = (int)x0f, y0 = (int)y0f;

    float cw[4]; int rr[4];
    {
        const int xs[4] = {x0, x0 + 1, x0, x0 + 1};
        const int ys[4] = {y0, y0, y0 + 1, y0 + 1};
        const float ws4[4] = {wx0 * wy0, wx1 * wy0, wx0 * wy1, wx1 * wy1};
        #pragma unroll
        for (int c = 0; c < 4; c++) {
            const bool valid = xs[c] >= 0 && xs[c] <= 13 && ys[c] >= 0 && ys[c] <= 13;
            cw[c] = valid ? ws4[c] : 0.0f;
            rr[c] = valid ? (ys[c] * 14 + xs[c]) * 768 : 0;
        }
    }

    const unsigned short* kb = Kb + (size_t)b * 196 * 768;
    const unsigned short* vb = Vb + (size_t)b * 196 * 768;

    shortx8 k16[4], v16[4];
    unsigned long long k8[4], v8[4];
    #pragma unroll
    for (int c = 0; c < 4; c++) {
        k16[c] = *(const shortx8*)&kb[rr[c] + d0];
        v16[c] = *(const shortx8*)&vb[rr[c] + d0];
        k8[c]  = *(const unsigned long long*)&kb[rr[c] + d1];
        v8[c]  = *(const unsigned long long*)&vb[rr[c] + d1];
    }

    float kx[12] = {}, vx[12] = {};
    #pragma unroll
    for (int c = 0; c < 4; c++) {
        #pragma unroll
        for (int e = 0; e < 8; e++) {
            kx[e] += cw[c] * bf2f((unsigned short)k16[c][e]);
            vx[e] += cw[c] * bf2f((unsigned short)v16[c][e]);
        }
        #pragma unroll
        for (int e = 0; e < 4; e++) {
            kx[8 + e] += cw[c] * bf2f((unsigned short)(k8[c] >> (16 * e)));
            vx[8 + e] += cw[c] * bf2f((unsigned short)(v8[c] >> (16 * e)));
        }
    }

    float partial = 0.0f;
    #pragma unroll
    for (int e = 0; e < 12; e++) partial += kx[e] * q[e];

    #pragma unroll
    for (int off = 32; off >= 1; off >>= 1)
        partial += __shfl_xor(partial, off, 64);
    const float sig = 1.0f / (1.0f + expf(-0.01f * partial));

    floatx4 o0, o1, o2;
    #pragma unroll
    for (int e = 0; e < 4; e++) {
        o0[e] = sig * vx[e];
        o1[e] = sig * vx[4 + e];
        o2[e] = sig * vx[8 + e];
    }
    *(floatx4*)&out[rowOff + d0]     = o0;
    *(floatx4*)&out[rowOff + d0 + 4] = o1;
    *(floatx4*)&out[rowOff + d1]     = o2;
}

extern "C" void kernel_launch(void* const* d_in, const int* in_sizes, int n_in,
                              void* d_out, int out_size, void* d_ws, size_t ws_size,
                              hipStream_t stream) {
    const float* x     = (const float*)d_in[0];
    const int*   ids   = (const int*)d_in[1];
    // d_in[2] = mask (unused by reference)
    const float* normx = (const float*)d_in[3];
    const float* normy = (const float*)d_in[4];
    const float* Wq    = (const float*)d_in[5];
    const float* bq    = (const float*)d_in[6];
    const float* Wk    = (const float*)d_in[7];
    const float* bk    = (const float*)d_in[8];
    const float* Wv    = (const float*)d_in[9];
    const float* bv    = (const float*)d_in[10];
    const float* avgs  = (const float*)d_in[11];
    const float* stds  = (const float*)d_in[12];
    float* out = (float*)d_out;

    const int B = 128, P = 196, D = 768;
    const int M = B * P;                         // 25088
    const size_t qkvElems = (size_t)M * D;       // 19,267,584
    const size_t wElems   = (size_t)D * D;       // 589,824

    // ws tiers (deterministic: ws_size constant across calls)
    const size_t tierA = (4 * qkvElems + 3 * wElems) * 2;  // +bf16 q  (~157.7 MB)
    const size_t tierB = (3 * qkvElems + 3 * wElems) * 2;  // bf16 X/W/k/v (~119 MB)

    const int nSampBlocks = 8 * 16 * 49;         // 6272 (4 p per block)

    if (ws_size >= tierB) {
        unsigned short* Xb = (unsigned short*)d_ws;
        unsigned short* Wb = Xb + qkvElems;
        unsigned short* k  = Wb + 3 * wElems;
        unsigned short* v  = k + qkvElems;
        unsigned short* qb = (ws_size >= tierA) ? (v + qkvElems) : nullptr;
        float* qf = (qb == nullptr) ? out : nullptr;

        const int nbX = (int)(qkvElems / 8 / 256);   // 9408
        const int nbW = (int)(wElems / 8 / 256);     // 288
        cvt4<<<nbX + 3 * nbW, 256, 0, stream>>>(
            x, Wq, Wk, Wv, Xb, Wb, Wb + wElems, Wb + 2 * wElems, nbX, nbW, nbW);

        // 256x256 tiles over M=25088 (98) x N=2304 (9) -> 882 blocks
        gemm_qkv_8ph<<<882, 512, 0, stream>>>(
            Xb, Wb, bq, bk, bv, qf, qb, k, v);

        sample_attend<<<nSampBlocks, 256, 0, stream>>>(
            qf, qb, k, v, normx, normy, ids, avgs, stds, out);
    } else {
        unsigned short* k = (unsigned short*)d_ws;
        unsigned short* v = k + qkvElems;

        dim3 gGemm(D / BN, M / BM, 3);
        gemm_qkv_f32<<<gGemm, 256, 0, stream>>>(
            x, Wq, Wk, Wv, bq, bk, bv, out, k, v, M, D, D);

        sample_attend<<<nSampBlocks, 256, 0, stream>>>(
            out, nullptr, k, v, normx, normy, ids, avgs, stds, out);
    }
}

// Round 9
// 308.839 us; speedup vs baseline: 1.1683x; 1.0140x over previous
//
#include <hip/hip_runtime.h>
#include <hip/hip_bf16.h>

typedef __attribute__((ext_vector_type(4))) float floatx4;
typedef __attribute__((ext_vector_type(8))) short shortx8;
typedef __attribute__((address_space(3))) void as3_void;
typedef const __attribute__((address_space(1))) void as1_void;

__device__ __forceinline__ unsigned short f2bf(float f) {
    unsigned int u; __builtin_memcpy(&u, &f, 4);
    u += 0x7FFFu + ((u >> 16) & 1u);   // RNE
    return (unsigned short)(u >> 16);
}
__device__ __forceinline__ float bf2f(unsigned short h) {
    unsigned int u = ((unsigned int)h) << 16;
    float f; __builtin_memcpy(&f, &u, 4); return f;
}
__device__ __forceinline__ shortx8 pack8(floatx4 lo, floatx4 hi) {
    shortx8 r;
    r[0] = (short)f2bf(lo[0]); r[1] = (short)f2bf(lo[1]);
    r[2] = (short)f2bf(lo[2]); r[3] = (short)f2bf(lo[3]);
    r[4] = (short)f2bf(hi[0]); r[5] = (short)f2bf(hi[1]);
    r[6] = (short)f2bf(hi[2]); r[7] = (short)f2bf(hi[3]);
    return r;
}
__device__ __forceinline__ void ld16(const unsigned short* g, unsigned short* l) {
    __builtin_amdgcn_global_load_lds((as1_void*)g, (as3_void*)l, 16, 0, 0);
}

#define MFMA1(d, a, b) d = __builtin_amdgcn_mfma_f32_16x16x32_bf16(a, b, d, 0, 0, 0)
#define BARm asm volatile("s_barrier" ::: "memory")

// ---------- fp32 -> bf16 pre-convert (4 segments in one launch) ----------
__global__ __launch_bounds__(256) void cvt4(
    const float* __restrict__ s0, const float* __restrict__ s1,
    const float* __restrict__ s2, const float* __restrict__ s3,
    unsigned short* __restrict__ d0, unsigned short* __restrict__ d1,
    unsigned short* __restrict__ d2, unsigned short* __restrict__ d3,
    int nb0, int nb1, int nb2)
{
    int bid = blockIdx.x;
    const float* s; unsigned short* d;
    if (bid < nb0)                  { s = s0; d = d0; }
    else if (bid < nb0 + nb1)       { s = s1; d = d1; bid -= nb0; }
    else if (bid < nb0 + nb1 + nb2) { s = s2; d = d2; bid -= nb0 + nb1; }
    else                            { s = s3; d = d3; bid -= nb0 + nb1 + nb2; }
    const size_t i = ((size_t)bid * 256 + threadIdx.x) * 8;
    const floatx4 lo = *(const floatx4*)(s + i);
    const floatx4 hi = *(const floatx4*)(s + i + 4);
    *(shortx8*)(d + i) = pack8(lo, hi);
}

// ---------- GEMM v8: round-8 8-phase (T1+T2+T3+T4+T5) + LDS-staged epilogue
// C[25088 x 2304] = Xb * Wb^T (N folded over q/k/v), K=768 -> 12 K-tiles of
// 64, 6 iterations x 8 phases. 8 waves (2M x 4N), per-wave 128x64 out.
// Round-8 measured: 116.9us, 760 TF, MfmaUtil 31%, FETCH 79.7 MB, conflicts 0.
// v8 change (write-amp fix): WRITE_SIZE was 157 vs 114 MB ideal -- the
// per-(row,n) 32-B global_store_short segments don't fill 64-B lines. New
// epilogue: after the K-loop's final barrier ALL LDS is dead and each wave's
// 128x64 bf16 tile = 16 KB -> 8 waves exactly fill the 128 KB. Each wave
// writes fragment-layout bf16 into ITS OWN region (128 ds_write_b16, <=2-way
// bank alias = free) then reads back linearly (16 ds_read_b128) and stores
// full 128-B row segments (fully-combined lines). Same-wave DS ordering +
// compiler lgkm waits -> no extra barrier. Same f2bf RNE -> bit-identical.
__global__ __launch_bounds__(512, 2) void gemm_qkv_8ph(
    const unsigned short* __restrict__ Xb,
    const unsigned short* __restrict__ Wb,   // 3 contiguous 768x768 = 2304x768
    const float* __restrict__ bq, const float* __restrict__ bk,
    const float* __restrict__ bv,
    float* __restrict__ Qf, unsigned short* __restrict__ Qb16,
    unsigned short* __restrict__ Kb, unsigned short* __restrict__ Vb)
{
    __shared__ __attribute__((aligned(16))) unsigned short As[2][2][8192];
    __shared__ __attribute__((aligned(16))) unsigned short Bs[2][2][8192];

    // bijective XCD swizzle for 882 blocks (q=110, r=2), y-grouped: the 9
    // n-tiles sharing an A-panel land on one XCD (measured FETCH 80 MB).
    const unsigned orig = blockIdx.x;
    const unsigned xcd = orig & 7u, loc = orig >> 3;
    const unsigned wg = (xcd < 2u ? xcd * 111u : 222u + (xcd - 2u) * 110u) + loc;
    const unsigned yb = wg / 9u;
    const unsigned nb = wg - yb * 9u;

    const int tid  = threadIdx.x;
    const int wave = tid >> 6, lane = tid & 63;
    const int fRow = lane & 15, gq = lane >> 4;
    const int wm2  = wave >> 2;            // A half (0/1)
    const int wn4  = wave & 3;
    const int hB   = wn4 >> 1;             // B half
    const int bRow0 = (wn4 & 1) * 64;      // row offset within B half
    const int mBlock = (int)yb * 256;
    const int nRow0  = (int)nb * 256;      // folded B row base

    // staging: thread t -> row (t>>3) (+64 for 2nd load), LDS slot t&7;
    // global col chunk = (t&7) ^ (row&7)  [swizzle involution, linear dest]
    const int srow0 = tid >> 3;
    const int scol  = ((tid & 7) ^ (srow0 & 7)) * 8;
    const int dOff  = tid * 8;

    auto stA = [&](int t, int h, int db) {
        const unsigned short* s =
            Xb + (size_t)(mBlock + h * 128 + srow0) * 768 + t * 64 + scol;
        unsigned short* d = &As[db][h][dOff];
        ld16(s, d);
        ld16(s + (size_t)64 * 768, d + 4096);
    };
    auto stB = [&](int t, int h, int db) {
        const unsigned short* s =
            Wb + (size_t)(nRow0 + h * 128 + srow0) * 768 + t * 64 + scol;
        unsigned short* d = &Bs[db][h][dOff];
        ld16(s, d);
        ld16(s + (size_t)64 * 768, d + 4096);
    };

    // read col (swizzled): want global chunk s*4+gq at row r (r&7 == fRow&7)
    const int rc0 = ((0 + gq) ^ (fRow & 7)) * 8;
    const int rc1 = ((4 + gq) ^ (fRow & 7)) * 8;

    floatx4 acc[8][4] = {};

    auto TILE = [&](int db, auto S0, auto S1, auto S2, auto S3, int ck) {
        shortx8 aF[4][2], bF[4][2];
        const unsigned short* Ah = As[db][wm2];
        const unsigned short* Bh = Bs[db][hB];
        // ---- q0: read A(ih0) 8 + B(n0,n1) 4; stage S0; MFMA (ih0, n0-1)
        #pragma unroll
        for (int ii = 0; ii < 4; ++ii) {
            const int rb = (ii * 16 + fRow) * 64;
            aF[ii][0] = *(const shortx8*)&Ah[rb + rc0];
            aF[ii][1] = *(const shortx8*)&Ah[rb + rc1];
        }
        #pragma unroll
        for (int nn = 0; nn < 2; ++nn) {
            const int rb = (bRow0 + nn * 16 + fRow) * 64;
            bF[nn][0] = *(const shortx8*)&Bh[rb + rc0];
            bF[nn][1] = *(const shortx8*)&Bh[rb + rc1];
        }
        S0();
        BARm;
        __builtin_amdgcn_s_setprio(1);
        #pragma unroll
        for (int ii = 0; ii < 4; ++ii)
            #pragma unroll
            for (int nn = 0; nn < 2; ++nn) {
                MFMA1(acc[ii][nn], aF[ii][0], bF[nn][0]);
                MFMA1(acc[ii][nn], aF[ii][1], bF[nn][1]);
            }
        __builtin_amdgcn_s_setprio(0);
        BARm;
        // ---- q1: read B(n2,n3) 4; stage S1; MFMA (ih0, n2-3)
        #pragma unroll
        for (int nn = 2; nn < 4; ++nn) {
            const int rb = (bRow0 + nn * 16 + fRow) * 64;
            bF[nn][0] = *(const shortx8*)&Bh[rb + rc0];
            bF[nn][1] = *(const shortx8*)&Bh[rb + rc1];
        }
        S1();
        BARm;
        __builtin_amdgcn_s_setprio(1);
        #pragma unroll
        for (int ii = 0; ii < 4; ++ii)
            #pragma unroll
            for (int nn = 2; nn < 4; ++nn) {
                MFMA1(acc[ii][nn], aF[ii][0], bF[nn][0]);
                MFMA1(acc[ii][nn], aF[ii][1], bF[nn][1]);
            }
        __builtin_amdgcn_s_setprio(0);
        BARm;
        // ---- q2: read A(ih1) 8 (reuse aF); stage S2; MFMA (ih1, n2-3)
        #pragma unroll
        for (int ii = 0; ii < 4; ++ii) {
            const int rb = ((ii + 4) * 16 + fRow) * 64;
            aF[ii][0] = *(const shortx8*)&Ah[rb + rc0];
            aF[ii][1] = *(const shortx8*)&Ah[rb + rc1];
        }
        S2();
        BARm;
        __builtin_amdgcn_s_setprio(1);
        #pragma unroll
        for (int ii = 0; ii < 4; ++ii)
            #pragma unroll
            for (int nn = 2; nn < 4; ++nn) {
                MFMA1(acc[4 + ii][nn], aF[ii][0], bF[nn][0]);
                MFMA1(acc[4 + ii][nn], aF[ii][1], bF[nn][1]);
            }
        __builtin_amdgcn_s_setprio(0);
        BARm;
        // ---- q3: stage S3; MFMA (ih1, n0-1); checkpoint; barrier
        S3();
        BARm;
        __builtin_amdgcn_s_setprio(1);
        #pragma unroll
        for (int ii = 0; ii < 4; ++ii)
            #pragma unroll
            for (int nn = 0; nn < 2; ++nn) {
                MFMA1(acc[4 + ii][nn], aF[ii][0], bF[nn][0]);
                MFMA1(acc[4 + ii][nn], aF[ii][1], bF[nn][1]);
            }
        __builtin_amdgcn_s_setprio(0);
        if (ck == 4)      { asm volatile("s_waitcnt vmcnt(4)" ::: "memory"); }
        else if (ck == 0) { asm volatile("s_waitcnt vmcnt(0)" ::: "memory"); }
        BARm;
    };

    // ---- prologue: tile 0 (4 halves) then B(1) (2 halves); wait tile 0 ----
    stA(0, 0, 0); stA(0, 1, 0); stB(0, 0, 0); stB(0, 1, 0);
    asm volatile("" ::: "memory");          // keep issue order for vmcnt math
    stB(1, 0, 1); stB(1, 1, 1);
    asm volatile("s_waitcnt vmcnt(4)" ::: "memory");
    BARm;

    for (int j = 0; j < 6; ++j) {
        const int t1 = 2 * j + 1, t2 = 2 * j + 2, t3 = 2 * j + 3;
        TILE(0,
             [&] { stA(t1, 0, 1); },
             [&] { stA(t1, 1, 1); },
             [&] { if (t2 < 12) stB(t2, 0, 0); },
             [&] { if (t2 < 12) stB(t2, 1, 0); },
             (j < 5) ? 4 : 0);
        TILE(1,
             [&] { if (t2 < 12) stA(t2, 0, 0); },
             [&] { if (t2 < 12) stA(t2, 1, 0); },
             [&] { if (t3 < 12) stB(t3, 0, 1); },
             [&] { if (t3 < 12) stB(t3, 1, 1); },
             (j < 5) ? 4 : -1);
    }

    // ---- epilogue: C/D col = lane&15, row = (lane>>4)*4 + reg ----
    const int z = (int)nb / 3;
    const int colBase = ((int)nb - z * 3) * 256 + wn4 * 64;
    const float* bias = (z == 0) ? bq : ((z == 1) ? bk : bv);
    const int rowBase = mBlock + wm2 * 128;
    if (z == 0 && Qb16 == nullptr) {
        #pragma unroll
        for (int n = 0; n < 4; ++n) {
            const int col = colBase + n * 16 + fRow;
            const float bvf = bias[col];
            #pragma unroll
            for (int i = 0; i < 8; ++i)
                #pragma unroll
                for (int r = 0; r < 4; ++r)
                    Qf[(size_t)(rowBase + i * 16 + gq * 4 + r) * 768 + col] =
                        acc[i][n][r] + bvf;
        }
    } else {
        unsigned short* Out = (z == 0) ? Qb16 : ((z == 1) ? Kb : Vb);
        float bvf[4];
        #pragma unroll
        for (int n = 0; n < 4; ++n) bvf[n] = bias[colBase + n * 16 + fRow];
        // LDS-staged store: wave's own 16 KB region (K-loop LDS is dead
        // after the final TILE barrier; last tail stages all skipped and
        // j=5 first TILE drained vmcnt(0) -> no in-flight LDS writes).
        unsigned short* myLds = (wave < 4)
            ? (&As[0][0][0] + wave * 8192)
            : (&Bs[0][0][0] + (wave - 4) * 8192);
        #pragma unroll
        for (int i = 0; i < 8; ++i)
            #pragma unroll
            for (int n = 0; n < 4; ++n)
                #pragma unroll
                for (int r = 0; r < 4; ++r)
                    myLds[(i * 16 + gq * 4 + r) * 64 + (n * 16 + fRow)] =
                        f2bf(acc[i][n][r] + bvf[n]);
        // read back linearly: 8 rows x 128 B per iteration, full-line stores
        const int rLane = lane >> 3, cChunk = (lane & 7) * 8;
        #pragma unroll
        for (int it = 0; it < 16; ++it) {
            const int row = it * 8 + rLane;
            const shortx8 vv = *(const shortx8*)&myLds[row * 64 + cChunk];
            *(shortx8*)&Out[(size_t)(rowBase + row) * 768 + colBase + cChunk] = vv;
        }
    }
}

#define BM 128
#define BN 128
#define BK 32

// ---------- fallback GEMM (proven): fp32 src, pack in kernel ----------
__global__ __launch_bounds__(256) void gemm_qkv_f32(
    const float* __restrict__ X,
    const float* __restrict__ Wq, const float* __restrict__ Wk,
    const float* __restrict__ Wv,
    const float* __restrict__ bq, const float* __restrict__ bk,
    const float* __restrict__ bv,
    float* __restrict__ Qf, unsigned short* __restrict__ Kb,
    unsigned short* __restrict__ Vb,
    int M, int N, int K)
{
    __shared__ __attribute__((aligned(16))) unsigned short As[BM * BK];
    __shared__ __attribute__((aligned(16))) unsigned short Bs[BN * BK];

    const float* W;  const float* bias;
    if (blockIdx.z == 0)      { W = Wq; bias = bq; }
    else if (blockIdx.z == 1) { W = Wk; bias = bk; }
    else                      { W = Wv; bias = bv; }

    const int tid  = threadIdx.x;
    const int wave = tid >> 6;
    const int lane = tid & 63;
    const int mBlock = blockIdx.y * BM;
    const int nBlock = blockIdx.x * BN;

    const int sRow = tid >> 1;
    const int sCol = (tid & 1) * 16;
    const float* Ag = X + (size_t)(mBlock + sRow) * K + sCol;
    const float* Bg = W + (size_t)(nBlock + sRow) * K + sCol;
    unsigned short* Al = &As[sRow * BK + sCol];
    unsigned short* Bl = &Bs[sRow * BK + sCol];

    floatx4 acc[4][4] = {};
    const int wm   = (wave >> 1) * 64;
    const int wn   = (wave & 1) * 64;
    const int fRow = lane & 15;
    const int fK   = (lane >> 4) * 8;

    for (int kt = 0; kt < K; kt += BK) {
        floatx4 a[4], b[4];
        #pragma unroll
        for (int c = 0; c < 4; c++) {
            a[c] = *(const floatx4*)(Ag + kt + c * 4);
            b[c] = *(const floatx4*)(Bg + kt + c * 4);
        }
        __syncthreads();
        *(shortx8*)(Al)     = pack8(a[0], a[1]);
        *(shortx8*)(Al + 8) = pack8(a[2], a[3]);
        *(shortx8*)(Bl)     = pack8(b[0], b[1]);
        *(shortx8*)(Bl + 8) = pack8(b[2], b[3]);
        __syncthreads();

        shortx8 af[4], bfr[4];
        #pragma unroll
        for (int i = 0; i < 4; i++) {
            af[i]  = *(const shortx8*)&As[(wm + i*16 + fRow) * BK + fK];
            bfr[i] = *(const shortx8*)&Bs[(wn + i*16 + fRow) * BK + fK];
        }
        #pragma unroll
        for (int i = 0; i < 4; i++)
            #pragma unroll
            for (int j = 0; j < 4; j++)
                acc[i][j] = __builtin_amdgcn_mfma_f32_16x16x32_bf16(
                    af[i], bfr[j], acc[i][j], 0, 0, 0);
    }

    const int cRow = (lane >> 4) * 4;
    const int cCol = lane & 15;
    if (blockIdx.z == 0) {
        #pragma unroll
        for (int j = 0; j < 4; j++) {
            const int col = nBlock + wn + j*16 + cCol;
            const float bvf = bias[col];
            #pragma unroll
            for (int i = 0; i < 4; i++)
                #pragma unroll
                for (int r = 0; r < 4; r++)
                    Qf[(size_t)(mBlock + wm + i*16 + cRow + r) * N + col] =
                        acc[i][j][r] + bvf;
        }
    } else {
        unsigned short* Out = (blockIdx.z == 1) ? Kb : Vb;
        #pragma unroll
        for (int j = 0; j < 4; j++) {
            const int col = nBlock + wn + j*16 + cCol;
            const float bvf = bias[col];
            #pragma unroll
            for (int i = 0; i < 4; i++)
                #pragma unroll
                for (int r = 0; r < 4; r++)
                    Out[(size_t)(mBlock + wm + i*16 + cRow + r) * N + col] =
                        f2bf(acc[i][j][r] + bvf);
        }
    }
}

// ---------- sampler v2b: 4 waves/block, b walked DESCENDING per XCD ----------
__global__ __launch_bounds__(256) void sample_attend(
    const float* __restrict__ Qf,            // fp32 q (if Qb16 == null)
    const unsigned short* __restrict__ Qb16, // bf16 q (preferred)
    const unsigned short* __restrict__ Kb,
    const unsigned short* __restrict__ Vb,
    const float* __restrict__ normx,
    const float* __restrict__ normy,
    const int* __restrict__ img_ids,
    const float* __restrict__ avgs,
    const float* __restrict__ stds,
    float* __restrict__ out)
{
    const unsigned g    = blockIdx.x;            // 0..6271
    const unsigned xcd  = g & 7;
    const unsigned slot = g >> 3;                // 0..783
    const int b = (int)(xcd * 16 + (15 - slot / 49));
    const int p = (int)((slot % 49) * 4 + (threadIdx.x >> 6));
    const int lane = threadIdx.x & 63;

    const size_t rowOff = ((size_t)b * 196 + p) * 768;
    const int d0 = lane * 8;                     // elems [d0, d0+8)
    const int d1 = 512 + lane * 4;               // elems [d1, d1+4)

    float q[12];
    if (Qb16 != nullptr) {
        const shortx8 q16 = *(const shortx8*)&Qb16[rowOff + d0];
        const unsigned long long q8 = *(const unsigned long long*)&Qb16[rowOff + d1];
        #pragma unroll
        for (int e = 0; e < 8; e++) q[e] = bf2f((unsigned short)q16[e]);
        #pragma unroll
        for (int e = 0; e < 4; e++) q[8 + e] = bf2f((unsigned short)(q8 >> (16 * e)));
    } else {
        const floatx4 qa = *(const floatx4*)&Qf[rowOff + d0];
        const floatx4 qb2 = *(const floatx4*)&Qf[rowOff + d0 + 4];
        const floatx4 qc = *(const floatx4*)&Qf[rowOff + d1];
        #pragma unroll
        for (int e = 0; e < 4; e++) { q[e] = qa[e]; q[4 + e] = qb2[e]; q[8 + e] = qc[e]; }
    }

    const int id = img_ids[b];
    auto coord = [&](int n) -> float {
        int c = 0;
        if (n >= 196) { n -= 196; c = 1; }
        const float base = (c == 0) ? normx[b * 196 + n] : normy[b * 196 + n];
        const float a = avgs[(size_t)id * 392 + c * 196 + n];
        const float s = stds[(size_t)id * 392 + c * 196 + n];
        return tanhf((base + a) * s);
    };
    const float gx = coord(2 * p);
    const float gy = coord(2 * p + 1);

    const float ix = ((gx + 1.0f) * 14.0f - 1.0f) * 0.5f;
    const float iy = ((gy + 1.0f) * 14.0f - 1.0f) * 0.5f;
    const float x0f = floorf(ix), y0f = floorf(iy);
    const float wx1 = ix - x0f, wx0 = 1.0f - wx1;
    const float wy1 = iy - y0f, wy0 = 1.0f - wy1;
    const int x0 = (int)x0f, y0 = (int)y0f;

    float cw[4]; int rr[4];
    {
        const int xs[4] = {x0, x0 + 1, x0, x0 + 1};
        const int ys[4] = {y0, y0, y0 + 1, y0 + 1};
        const float ws4[4] = {wx0 * wy0, wx1 * wy0, wx0 * wy1, wx1 * wy1};
        #pragma unroll
        for (int c = 0; c < 4; c++) {
            const bool valid = xs[c] >= 0 && xs[c] <= 13 && ys[c] >= 0 && ys[c] <= 13;
            cw[c] = valid ? ws4[c] : 0.0f;
            rr[c] = valid ? (ys[c] * 14 + xs[c]) * 768 : 0;
        }
    }

    const unsigned short* kb = Kb + (size_t)b * 196 * 768;
    const unsigned short* vb = Vb + (size_t)b * 196 * 768;

    shortx8 k16[4], v16[4];
    unsigned long long k8[4], v8[4];
    #pragma unroll
    for (int c = 0; c < 4; c++) {
        k16[c] = *(const shortx8*)&kb[rr[c] + d0];
        v16[c] = *(const shortx8*)&vb[rr[c] + d0];
        k8[c]  = *(const unsigned long long*)&kb[rr[c] + d1];
        v8[c]  = *(const unsigned long long*)&vb[rr[c] + d1];
    }

    float kx[12] = {}, vx[12] = {};
    #pragma unroll
    for (int c = 0; c < 4; c++) {
        #pragma unroll
        for (int e = 0; e < 8; e++) {
            kx[e] += cw[c] * bf2f((unsigned short)k16[c][e]);
            vx[e] += cw[c] * bf2f((unsigned short)v16[c][e]);
        }
        #pragma unroll
        for (int e = 0; e < 4; e++) {
            kx[8 + e] += cw[c] * bf2f((unsigned short)(k8[c] >> (16 * e)));
            vx[8 + e] += cw[c] * bf2f((unsigned short)(v8[c] >> (16 * e)));
        }
    }

    float partial = 0.0f;
    #pragma unroll
    for (int e = 0; e < 12; e++) partial += kx[e] * q[e];

    #pragma unroll
    for (int off = 32; off >= 1; off >>= 1)
        partial += __shfl_xor(partial, off, 64);
    const float sig = 1.0f / (1.0f + expf(-0.01f * partial));

    floatx4 o0, o1, o2;
    #pragma unroll
    for (int e = 0; e < 4; e++) {
        o0[e] = sig * vx[e];
        o1[e] = sig * vx[4 + e];
        o2[e] = sig * vx[8 + e];
    }
    *(floatx4*)&out[rowOff + d0]     = o0;
    *(floatx4*)&out[rowOff + d0 + 4] = o1;
    *(floatx4*)&out[rowOff + d1]     = o2;
}

extern "C" void kernel_launch(void* const* d_in, const int* in_sizes, int n_in,
                              void* d_out, int out_size, void* d_ws, size_t ws_size,
                              hipStream_t stream) {
    const float* x     = (const float*)d_in[0];
    const int*   ids   = (const int*)d_in[1];
    // d_in[2] = mask (unused by reference)
    const float* normx = (const float*)d_in[3];
    const float* normy = (const float*)d_in[4];
    const float* Wq    = (const float*)d_in[5];
    const float* bq    = (const float*)d_in[6];
    const float* Wk    = (const float*)d_in[7];
    const float* bk    = (const float*)d_in[8];
    const float* Wv    = (const float*)d_in[9];
    const float* bv    = (const float*)d_in[10];
    const float* avgs  = (const float*)d_in[11];
    const float* stds  = (const float*)d_in[12];
    float* out = (float*)d_out;

    const int B = 128, P = 196, D = 768;
    const int M = B * P;                         // 25088
    const size_t qkvElems = (size_t)M * D;       // 19,267,584
    const size_t wElems   = (size_t)D * D;       // 589,824

    // ws tiers (deterministic: ws_size constant across calls)
    const size_t tierA = (4 * qkvElems + 3 * wElems) * 2;  // +bf16 q  (~157.7 MB)
    const size_t tierB = (3 * qkvElems + 3 * wElems) * 2;  // bf16 X/W/k/v (~119 MB)

    const int nSampBlocks = 8 * 16 * 49;         // 6272 (4 p per block)

    if (ws_size >= tierB) {
        unsigned short* Xb = (unsigned short*)d_ws;
        unsigned short* Wb = Xb + qkvElems;
        unsigned short* k  = Wb + 3 * wElems;
        unsigned short* v  = k + qkvElems;
        unsigned short* qb = (ws_size >= tierA) ? (v + qkvElems) : nullptr;
        float* qf = (qb == nullptr) ? out : nullptr;

        const int nbX = (int)(qkvElems / 8 / 256);   // 9408
        const int nbW = (int)(wElems / 8 / 256);     // 288
        cvt4<<<nbX + 3 * nbW, 256, 0, stream>>>(
            x, Wq, Wk, Wv, Xb, Wb, Wb + wElems, Wb + 2 * wElems, nbX, nbW, nbW);

        // 256x256 tiles over M=25088 (98) x N=2304 (9) -> 882 blocks
        gemm_qkv_8ph<<<882, 512, 0, stream>>>(
            Xb, Wb, bq, bk, bv, qf, qb, k, v);

        sample_attend<<<nSampBlocks, 256, 0, stream>>>(
            qf, qb, k, v, normx, normy, ids, avgs, stds, out);
    } else {
        unsigned short* k = (unsigned short*)d_ws;
        unsigned short* v = k + qkvElems;

        dim3 gGemm(D / BN, M / BM, 3);
        gemm_qkv_f32<<<gGemm, 256, 0, stream>>>(
            x, Wq, Wk, Wv, bq, bk, bv, out, k, v, M, D, D);

        sample_attend<<<nSampBlocks, 256, 0, stream>>>(
            out, nullptr, k, v, normx, normy, ids, avgs, stds, out);
    }
}

// Round 10
// 302.556 us; speedup vs baseline: 1.1926x; 1.0208x over previous
//
#include <hip/hip_runtime.h>
#include <hip/hip_bf16.h>

typedef __attribute__((ext_vector_type(4))) float floatx4;
typedef __attribute__((ext_vector_type(4))) int intx4;
typedef __attribute__((ext_vector_type(8))) short shortx8;
typedef __attribute__((address_space(3))) void as3_void;
typedef const __attribute__((address_space(1))) void as1_void;

__device__ __forceinline__ unsigned short f2bf(float f) {
    unsigned int u; __builtin_memcpy(&u, &f, 4);
    u += 0x7FFFu + ((u >> 16) & 1u);   // RNE
    return (unsigned short)(u >> 16);
}
__device__ __forceinline__ float bf2f(unsigned short h) {
    unsigned int u = ((unsigned int)h) << 16;
    float f; __builtin_memcpy(&f, &u, 4); return f;
}
__device__ __forceinline__ shortx8 pack8(floatx4 lo, floatx4 hi) {
    shortx8 r;
    r[0] = (short)f2bf(lo[0]); r[1] = (short)f2bf(lo[1]);
    r[2] = (short)f2bf(lo[2]); r[3] = (short)f2bf(lo[3]);
    r[4] = (short)f2bf(hi[0]); r[5] = (short)f2bf(hi[1]);
    r[6] = (short)f2bf(hi[2]); r[7] = (short)f2bf(hi[3]);
    return r;
}
__device__ __forceinline__ void ld16(const unsigned short* g, unsigned short* l) {
    __builtin_amdgcn_global_load_lds((as1_void*)g, (as3_void*)l, 16, 0, 0);
}

#define MFMA1(d, a, b) d = __builtin_amdgcn_mfma_f32_16x16x32_bf16(a, b, d, 0, 0, 0)
#define BARm asm volatile("s_barrier" ::: "memory")

// ---------- fp32->bf16 convert (4 segs) + coord precompute appendage ------
// Coord blocks (bid >= nconv): one thread per (b,p); does the sampler's
// whole coordinate pipeline (6 scattered loads + 2 tanhf + bilinear) and
// writes {cw[4] fp32, rr[4] int} = 32 B to cgrid. Moves ~500-700 cyc of
// serial latency off the sampler's per-wave critical path into this
// BW-bound kernel's idle VALU/latency slots. Verbatim math = bit-identical.
__global__ __launch_bounds__(256) void cvt4(
    const float* __restrict__ s0, const float* __restrict__ s1,
    const float* __restrict__ s2, const float* __restrict__ s3,
    unsigned short* __restrict__ d0, unsigned short* __restrict__ d1,
    unsigned short* __restrict__ d2, unsigned short* __restrict__ d3,
    int nb0, int nb1, int nb2, int nb3,
    const float* __restrict__ normx, const float* __restrict__ normy,
    const int* __restrict__ img_ids, const float* __restrict__ avgs,
    const float* __restrict__ stds, float* __restrict__ cgrid)
{
    int bid = blockIdx.x;
    const int nconv = nb0 + nb1 + nb2 + nb3;
    if (bid < nconv) {
        const float* s; unsigned short* d;
        if (bid < nb0)                  { s = s0; d = d0; }
        else if (bid < nb0 + nb1)       { s = s1; d = d1; bid -= nb0; }
        else if (bid < nb0 + nb1 + nb2) { s = s2; d = d2; bid -= nb0 + nb1; }
        else                            { s = s3; d = d3; bid -= nb0 + nb1 + nb2; }
        const size_t i = ((size_t)bid * 256 + threadIdx.x) * 8;
        const floatx4 lo = *(const floatx4*)(s + i);
        const floatx4 hi = *(const floatx4*)(s + i + 4);
        *(shortx8*)(d + i) = pack8(lo, hi);
        return;
    }
    // ---- coord precompute: idx = b*196 + p ----
    const int idx = (bid - nconv) * 256 + (int)threadIdx.x;   // 0..25087
    const int b = idx / 196, p = idx - b * 196;
    const int id = img_ids[b];
    auto coord = [&](int n) -> float {
        int c = 0;
        if (n >= 196) { n -= 196; c = 1; }
        const float base = (c == 0) ? normx[b * 196 + n] : normy[b * 196 + n];
        const float a = avgs[(size_t)id * 392 + c * 196 + n];
        const float s = stds[(size_t)id * 392 + c * 196 + n];
        return tanhf((base + a) * s);
    };
    const float gx = coord(2 * p);
    const float gy = coord(2 * p + 1);
    const float ix = ((gx + 1.0f) * 14.0f - 1.0f) * 0.5f;
    const float iy = ((gy + 1.0f) * 14.0f - 1.0f) * 0.5f;
    const float x0f = floorf(ix), y0f = floorf(iy);
    const float wx1 = ix - x0f, wx0 = 1.0f - wx1;
    const float wy1 = iy - y0f, wy0 = 1.0f - wy1;
    const int x0 = (int)x0f, y0 = (int)y0f;
    const int xs[4] = {x0, x0 + 1, x0, x0 + 1};
    const int ys[4] = {y0, y0, y0 + 1, y0 + 1};
    const float ws4[4] = {wx0 * wy0, wx1 * wy0, wx0 * wy1, wx1 * wy1};
    floatx4 cwv; intx4 rrv;
    #pragma unroll
    for (int c = 0; c < 4; c++) {
        const bool valid = xs[c] >= 0 && xs[c] <= 13 && ys[c] >= 0 && ys[c] <= 13;
        cwv[c] = valid ? ws4[c] : 0.0f;
        rrv[c] = valid ? (ys[c] * 14 + xs[c]) * 768 : 0;
    }
    float* cg = cgrid + (size_t)idx * 8;
    *(floatx4*)cg = cwv;
    *(intx4*)(cg + 4) = rrv;
}

// ---------- GEMM v8 (FROZEN from round 9): 8-phase + LDS-staged epilogue --
// Measured r9: 112.9us, 787 TF, FETCH 79.7 MB (analytic min), WRITE 112.9 MB
// (analytic min), conflicts 1.8e6 (epilogue-only), MfmaUtil 32%.
__global__ __launch_bounds__(512, 2) void gemm_qkv_8ph(
    const unsigned short* __restrict__ Xb,
    const unsigned short* __restrict__ Wb,   // 3 contiguous 768x768 = 2304x768
    const float* __restrict__ bq, const float* __restrict__ bk,
    const float* __restrict__ bv,
    float* __restrict__ Qf, unsigned short* __restrict__ Qb16,
    unsigned short* __restrict__ Kb, unsigned short* __restrict__ Vb)
{
    __shared__ __attribute__((aligned(16))) unsigned short As[2][2][8192];
    __shared__ __attribute__((aligned(16))) unsigned short Bs[2][2][8192];

    const unsigned orig = blockIdx.x;
    const unsigned xcd = orig & 7u, loc = orig >> 3;
    const unsigned wg = (xcd < 2u ? xcd * 111u : 222u + (xcd - 2u) * 110u) + loc;
    const unsigned yb = wg / 9u;
    const unsigned nb = wg - yb * 9u;

    const int tid  = threadIdx.x;
    const int wave = tid >> 6, lane = tid & 63;
    const int fRow = lane & 15, gq = lane >> 4;
    const int wm2  = wave >> 2;
    const int wn4  = wave & 3;
    const int hB   = wn4 >> 1;
    const int bRow0 = (wn4 & 1) * 64;
    const int mBlock = (int)yb * 256;
    const int nRow0  = (int)nb * 256;

    const int srow0 = tid >> 3;
    const int scol  = ((tid & 7) ^ (srow0 & 7)) * 8;
    const int dOff  = tid * 8;

    auto stA = [&](int t, int h, int db) {
        const unsigned short* s =
            Xb + (size_t)(mBlock + h * 128 + srow0) * 768 + t * 64 + scol;
        unsigned short* d = &As[db][h][dOff];
        ld16(s, d);
        ld16(s + (size_t)64 * 768, d + 4096);
    };
    auto stB = [&](int t, int h, int db) {
        const unsigned short* s =
            Wb + (size_t)(nRow0 + h * 128 + srow0) * 768 + t * 64 + scol;
        unsigned short* d = &Bs[db][h][dOff];
        ld16(s, d);
        ld16(s + (size_t)64 * 768, d + 4096);
    };

    const int rc0 = ((0 + gq) ^ (fRow & 7)) * 8;
    const int rc1 = ((4 + gq) ^ (fRow & 7)) * 8;

    floatx4 acc[8][4] = {};

    auto TILE = [&](int db, auto S0, auto S1, auto S2, auto S3, int ck) {
        shortx8 aF[4][2], bF[4][2];
        const unsigned short* Ah = As[db][wm2];
        const unsigned short* Bh = Bs[db][hB];
        #pragma unroll
        for (int ii = 0; ii < 4; ++ii) {
            const int rb = (ii * 16 + fRow) * 64;
            aF[ii][0] = *(const shortx8*)&Ah[rb + rc0];
            aF[ii][1] = *(const shortx8*)&Ah[rb + rc1];
        }
        #pragma unroll
        for (int nn = 0; nn < 2; ++nn) {
            const int rb = (bRow0 + nn * 16 + fRow) * 64;
            bF[nn][0] = *(const shortx8*)&Bh[rb + rc0];
            bF[nn][1] = *(const shortx8*)&Bh[rb + rc1];
        }
        S0();
        BARm;
        __builtin_amdgcn_s_setprio(1);
        #pragma unroll
        for (int ii = 0; ii < 4; ++ii)
            #pragma unroll
            for (int nn = 0; nn < 2; ++nn) {
                MFMA1(acc[ii][nn], aF[ii][0], bF[nn][0]);
                MFMA1(acc[ii][nn], aF[ii][1], bF[nn][1]);
            }
        __builtin_amdgcn_s_setprio(0);
        BARm;
        #pragma unroll
        for (int nn = 2; nn < 4; ++nn) {
            const int rb = (bRow0 + nn * 16 + fRow) * 64;
            bF[nn][0] = *(const shortx8*)&Bh[rb + rc0];
            bF[nn][1] = *(const shortx8*)&Bh[rb + rc1];
        }
        S1();
        BARm;
        __builtin_amdgcn_s_setprio(1);
        #pragma unroll
        for (int ii = 0; ii < 4; ++ii)
            #pragma unroll
            for (int nn = 2; nn < 4; ++nn) {
                MFMA1(acc[ii][nn], aF[ii][0], bF[nn][0]);
                MFMA1(acc[ii][nn], aF[ii][1], bF[nn][1]);
            }
        __builtin_amdgcn_s_setprio(0);
        BARm;
        #pragma unroll
        for (int ii = 0; ii < 4; ++ii) {
            const int rb = ((ii + 4) * 16 + fRow) * 64;
            aF[ii][0] = *(const shortx8*)&Ah[rb + rc0];
            aF[ii][1] = *(const shortx8*)&Ah[rb + rc1];
        }
        S2();
        BARm;
        __builtin_amdgcn_s_setprio(1);
        #pragma unroll
        for (int ii = 0; ii < 4; ++ii)
            #pragma unroll
            for (int nn = 2; nn < 4; ++nn) {
                MFMA1(acc[4 + ii][nn], aF[ii][0], bF[nn][0]);
                MFMA1(acc[4 + ii][nn], aF[ii][1], bF[nn][1]);
            }
        __builtin_amdgcn_s_setprio(0);
        BARm;
        S3();
        BARm;
        __builtin_amdgcn_s_setprio(1);
        #pragma unroll
        for (int ii = 0; ii < 4; ++ii)
            #pragma unroll
            for (int nn = 0; nn < 2; ++nn) {
                MFMA1(acc[4 + ii][nn], aF[ii][0], bF[nn][0]);
                MFMA1(acc[4 + ii][nn], aF[ii][1], bF[nn][1]);
            }
        __builtin_amdgcn_s_setprio(0);
        if (ck == 4)      { asm volatile("s_waitcnt vmcnt(4)" ::: "memory"); }
        else if (ck == 0) { asm volatile("s_waitcnt vmcnt(0)" ::: "memory"); }
        BARm;
    };

    stA(0, 0, 0); stA(0, 1, 0); stB(0, 0, 0); stB(0, 1, 0);
    asm volatile("" ::: "memory");
    stB(1, 0, 1); stB(1, 1, 1);
    asm volatile("s_waitcnt vmcnt(4)" ::: "memory");
    BARm;

    for (int j = 0; j < 6; ++j) {
        const int t1 = 2 * j + 1, t2 = 2 * j + 2, t3 = 2 * j + 3;
        TILE(0,
             [&] { stA(t1, 0, 1); },
             [&] { stA(t1, 1, 1); },
             [&] { if (t2 < 12) stB(t2, 0, 0); },
             [&] { if (t2 < 12) stB(t2, 1, 0); },
             (j < 5) ? 4 : 0);
        TILE(1,
             [&] { if (t2 < 12) stA(t2, 0, 0); },
             [&] { if (t2 < 12) stA(t2, 1, 0); },
             [&] { if (t3 < 12) stB(t3, 0, 1); },
             [&] { if (t3 < 12) stB(t3, 1, 1); },
             (j < 5) ? 4 : -1);
    }

    const int z = (int)nb / 3;
    const int colBase = ((int)nb - z * 3) * 256 + wn4 * 64;
    const float* bias = (z == 0) ? bq : ((z == 1) ? bk : bv);
    const int rowBase = mBlock + wm2 * 128;
    if (z == 0 && Qb16 == nullptr) {
        #pragma unroll
        for (int n = 0; n < 4; ++n) {
            const int col = colBase + n * 16 + fRow;
            const float bvf = bias[col];
            #pragma unroll
            for (int i = 0; i < 8; ++i)
                #pragma unroll
                for (int r = 0; r < 4; ++r)
                    Qf[(size_t)(rowBase + i * 16 + gq * 4 + r) * 768 + col] =
                        acc[i][n][r] + bvf;
        }
    } else {
        unsigned short* Out = (z == 0) ? Qb16 : ((z == 1) ? Kb : Vb);
        float bvf[4];
        #pragma unroll
        for (int n = 0; n < 4; ++n) bvf[n] = bias[colBase + n * 16 + fRow];
        unsigned short* myLds = (wave < 4)
            ? (&As[0][0][0] + wave * 8192)
            : (&Bs[0][0][0] + (wave - 4) * 8192);
        #pragma unroll
        for (int i = 0; i < 8; ++i)
            #pragma unroll
            for (int n = 0; n < 4; ++n)
                #pragma unroll
                for (int r = 0; r < 4; ++r)
                    myLds[(i * 16 + gq * 4 + r) * 64 + (n * 16 + fRow)] =
                        f2bf(acc[i][n][r] + bvf[n]);
        const int rLane = lane >> 3, cChunk = (lane & 7) * 8;
        #pragma unroll
        for (int it = 0; it < 16; ++it) {
            const int row = it * 8 + rLane;
            const shortx8 vv = *(const shortx8*)&myLds[row * 64 + cChunk];
            *(shortx8*)&Out[(size_t)(rowBase + row) * 768 + colBase + cChunk] = vv;
        }
    }
}

#define BM 128
#define BN 128
#define BK 32

// ---------- fallback GEMM (proven): fp32 src, pack in kernel ----------
__global__ __launch_bounds__(256) void gemm_qkv_f32(
    const float* __restrict__ X,
    const float* __restrict__ Wq, const float* __restrict__ Wk,
    const float* __restrict__ Wv,
    const float* __restrict__ bq, const float* __restrict__ bk,
    const float* __restrict__ bv,
    float* __restrict__ Qf, unsigned short* __restrict__ Kb,
    unsigned short* __restrict__ Vb,
    int M, int N, int K)
{
    __shared__ __attribute__((aligned(16))) unsigned short As[BM * BK];
    __shared__ __attribute__((aligned(16))) unsigned short Bs[BN * BK];

    const float* W;  const float* bias;
    if (blockIdx.z == 0)      { W = Wq; bias = bq; }
    else if (blockIdx.z == 1) { W = Wk; bias = bk; }
    else                      { W = Wv; bias = bv; }

    const int tid  = threadIdx.x;
    const int wave = tid >> 6;
    const int lane = tid & 63;
    const int mBlock = blockIdx.y * BM;
    const int nBlock = blockIdx.x * BN;

    const int sRow = tid >> 1;
    const int sCol = (tid & 1) * 16;
    const float* Ag = X + (size_t)(mBlock + sRow) * K + sCol;
    const float* Bg = W + (size_t)(nBlock + sRow) * K + sCol;
    unsigned short* Al = &As[sRow * BK + sCol];
    unsigned short* Bl = &Bs[sRow * BK + sCol];

    floatx4 acc[4][4] = {};
    const int wm   = (wave >> 1) * 64;
    const int wn   = (wave & 1) * 64;
    const int fRow = lane & 15;
    const int fK   = (lane >> 4) * 8;

    for (int kt = 0; kt < K; kt += BK) {
        floatx4 a[4], b[4];
        #pragma unroll
        for (int c = 0; c < 4; c++) {
            a[c] = *(const floatx4*)(Ag + kt + c * 4);
            b[c] = *(const floatx4*)(Bg + kt + c * 4);
        }
        __syncthreads();
        *(shortx8*)(Al)     = pack8(a[0], a[1]);
        *(shortx8*)(Al + 8) = pack8(a[2], a[3]);
        *(shortx8*)(Bl)     = pack8(b[0], b[1]);
        *(shortx8*)(Bl + 8) = pack8(b[2], b[3]);
        __syncthreads();

        shortx8 af[4], bfr[4];
        #pragma unroll
        for (int i = 0; i < 4; i++) {
            af[i]  = *(const shortx8*)&As[(wm + i*16 + fRow) * BK + fK];
            bfr[i] = *(const shortx8*)&Bs[(wn + i*16 + fRow) * BK + fK];
        }
        #pragma unroll
        for (int i = 0; i < 4; i++)
            #pragma unroll
            for (int j = 0; j < 4; j++)
                acc[i][j] = __builtin_amdgcn_mfma_f32_16x16x32_bf16(
                    af[i], bfr[j], acc[i][j], 0, 0, 0);
    }

    const int cRow = (lane >> 4) * 4;
    const int cCol = lane & 15;
    if (blockIdx.z == 0) {
        #pragma unroll
        for (int j = 0; j < 4; j++) {
            const int col = nBlock + wn + j*16 + cCol;
            const float bvf = bias[col];
            #pragma unroll
            for (int i = 0; i < 4; i++)
                #pragma unroll
                for (int r = 0; r < 4; r++)
                    Qf[(size_t)(mBlock + wm + i*16 + cRow + r) * N + col] =
                        acc[i][j][r] + bvf;
        }
    } else {
        unsigned short* Out = (blockIdx.z == 1) ? Kb : Vb;
        #pragma unroll
        for (int j = 0; j < 4; j++) {
            const int col = nBlock + wn + j*16 + cCol;
            const float bvf = bias[col];
            #pragma unroll
            for (int i = 0; i < 4; i++)
                #pragma unroll
                for (int r = 0; r < 4; r++)
                    Out[(size_t)(mBlock + wm + i*16 + cRow + r) * N + col] =
                        f2bf(acc[i][j][r] + bvf);
        }
    }
}

// ---------- sampler v3: precomputed coords (cgrid) + descending-b ----------
// If cgrid != null the per-wave critical-path head (6 scattered loads +
// 2 tanhf + bilinear) collapses to one broadcast 32-B record load; the 16
// k/v gathers issue immediately. Inline-coord path kept as fallback.
__global__ __launch_bounds__(256) void sample_attend(
    const float* __restrict__ Qf,            // fp32 q (if Qb16 == null)
    const unsigned short* __restrict__ Qb16, // bf16 q (preferred)
    const unsigned short* __restrict__ Kb,
    const unsigned short* __restrict__ Vb,
    const float* __restrict__ normx,
    const float* __restrict__ normy,
    const int* __restrict__ img_ids,
    const float* __restrict__ avgs,
    const float* __restrict__ stds,
    const float* __restrict__ cgrid,         // precomputed {cw[4], rr[4]} or null
    float* __restrict__ out)
{
    const unsigned g    = blockIdx.x;            // 0..6271
    const unsigned xcd  = g & 7;
    const unsigned slot = g >> 3;                // 0..783
    const int b = (int)(xcd * 16 + (15 - slot / 49));
    const int p = (int)((slot % 49) * 4 + (threadIdx.x >> 6));
    const int lane = threadIdx.x & 63;

    const size_t rowOff = ((size_t)b * 196 + p) * 768;
    const int d0 = lane * 8;                     // elems [d0, d0+8)
    const int d1 = 512 + lane * 4;               // elems [d1, d1+4)

    float cw[4]; int rr[4];
    if (cgrid != nullptr) {
        const float* cg = cgrid + (size_t)(b * 196 + p) * 8;
        const floatx4 cwv = *(const floatx4*)cg;
        const intx4 rrv = *(const intx4*)(cg + 4);
        #pragma unroll
        for (int c = 0; c < 4; c++) { cw[c] = cwv[c]; rr[c] = rrv[c]; }
    } else {
        const int id = img_ids[b];
        auto coord = [&](int n) -> float {
            int c = 0;
            if (n >= 196) { n -= 196; c = 1; }
            const float base = (c == 0) ? normx[b * 196 + n] : normy[b * 196 + n];
            const float a = avgs[(size_t)id * 392 + c * 196 + n];
            const float s = stds[(size_t)id * 392 + c * 196 + n];
            return tanhf((base + a) * s);
        };
        const float gx = coord(2 * p);
        const float gy = coord(2 * p + 1);
        const float ix = ((gx + 1.0f) * 14.0f - 1.0f) * 0.5f;
        const float iy = ((gy + 1.0f) * 14.0f - 1.0f) * 0.5f;
        const float x0f = floorf(ix), y0f = floorf(iy);
        const float wx1 = ix - x0f, wx0 = 1.0f - wx1;
        const float wy1 = iy - y0f, wy0 = 1.0f - wy1;
        const int x0 = (int)x0f, y0 = (int)y0f;
        const int xs[4] = {x0, x0 + 1, x0, x0 + 1};
        const int ys[4] = {y0, y0, y0 + 1, y0 + 1};
        const float ws4[4] = {wx0 * wy0, wx1 * wy0, wx0 * wy1, wx1 * wy1};
        #pragma unroll
        for (int c = 0; c < 4; c++) {
            const bool valid = xs[c] >= 0 && xs[c] <= 13 && ys[c] >= 0 && ys[c] <= 13;
            cw[c] = valid ? ws4[c] : 0.0f;
            rr[c] = valid ? (ys[c] * 14 + xs[c]) * 768 : 0;
        }
    }

    const unsigned short* kb = Kb + (size_t)b * 196 * 768;
    const unsigned short* vb = Vb + (size_t)b * 196 * 768;

    // ---- gather all corner streams (independent loads, MLP-friendly) ----
    shortx8 k16[4], v16[4];
    unsigned long long k8[4], v8[4];
    #pragma unroll
    for (int c = 0; c < 4; c++) {
        k16[c] = *(const shortx8*)&kb[rr[c] + d0];
        v16[c] = *(const shortx8*)&vb[rr[c] + d0];
        k8[c]  = *(const unsigned long long*)&kb[rr[c] + d1];
        v8[c]  = *(const unsigned long long*)&vb[rr[c] + d1];
    }

    float q[12];
    if (Qb16 != nullptr) {
        const shortx8 q16 = *(const shortx8*)&Qb16[rowOff + d0];
        const unsigned long long q8 = *(const unsigned long long*)&Qb16[rowOff + d1];
        #pragma unroll
        for (int e = 0; e < 8; e++) q[e] = bf2f((unsigned short)q16[e]);
        #pragma unroll
        for (int e = 0; e < 4; e++) q[8 + e] = bf2f((unsigned short)(q8 >> (16 * e)));
    } else {
        const floatx4 qa = *(const floatx4*)&Qf[rowOff + d0];
        const floatx4 qb2 = *(const floatx4*)&Qf[rowOff + d0 + 4];
        const floatx4 qc = *(const floatx4*)&Qf[rowOff + d1];
        #pragma unroll
        for (int e = 0; e < 4; e++) { q[e] = qa[e]; q[4 + e] = qb2[e]; q[8 + e] = qc[e]; }
    }

    float kx[12] = {}, vx[12] = {};
    #pragma unroll
    for (int c = 0; c < 4; c++) {
        #pragma unroll
        for (int e = 0; e < 8; e++) {
            kx[e] += cw[c] * bf2f((unsigned short)k16[c][e]);
            vx[e] += cw[c] * bf2f((unsigned short)v16[c][e]);
        }
        #pragma unroll
        for (int e = 0; e < 4; e++) {
            kx[8 + e] += cw[c] * bf2f((unsigned short)(k8[c] >> (16 * e)));
            vx[8 + e] += cw[c] * bf2f((unsigned short)(v8[c] >> (16 * e)));
        }
    }

    float partial = 0.0f;
    #pragma unroll
    for (int e = 0; e < 12; e++) partial += kx[e] * q[e];

    #pragma unroll
    for (int off = 32; off >= 1; off >>= 1)
        partial += __shfl_xor(partial, off, 64);
    const float sig = 1.0f / (1.0f + expf(-0.01f * partial));

    floatx4 o0, o1, o2;
    #pragma unroll
    for (int e = 0; e < 4; e++) {
        o0[e] = sig * vx[e];
        o1[e] = sig * vx[4 + e];
        o2[e] = sig * vx[8 + e];
    }
    *(floatx4*)&out[rowOff + d0]     = o0;
    *(floatx4*)&out[rowOff + d0 + 4] = o1;
    *(floatx4*)&out[rowOff + d1]     = o2;
}

extern "C" void kernel_launch(void* const* d_in, const int* in_sizes, int n_in,
                              void* d_out, int out_size, void* d_ws, size_t ws_size,
                              hipStream_t stream) {
    const float* x     = (const float*)d_in[0];
    const int*   ids   = (const int*)d_in[1];
    // d_in[2] = mask (unused by reference)
    const float* normx = (const float*)d_in[3];
    const float* normy = (const float*)d_in[4];
    const float* Wq    = (const float*)d_in[5];
    const float* bq    = (const float*)d_in[6];
    const float* Wk    = (const float*)d_in[7];
    const float* bk    = (const float*)d_in[8];
    const float* Wv    = (const float*)d_in[9];
    const float* bv    = (const float*)d_in[10];
    const float* avgs  = (const float*)d_in[11];
    const float* stds  = (const float*)d_in[12];
    float* out = (float*)d_out;

    const int B = 128, P = 196, D = 768;
    const int M = B * P;                         // 25088
    const size_t qkvElems = (size_t)M * D;       // 19,267,584
    const size_t wElems   = (size_t)D * D;       // 589,824
    const size_t coordFl  = (size_t)M * 8;       // cw[4]+rr[4] per (b,p)

    // ws tiers (deterministic: ws_size constant across calls)
    const size_t tierA = (4 * qkvElems + 3 * wElems) * 2;      // +bf16 q (~157.7 MB)
    const size_t tierC = tierA + coordFl * 4;                  // +coord grid (~158.5 MB)
    const size_t tierB = (3 * qkvElems + 3 * wElems) * 2;      // bf16 X/W/k/v (~119 MB)

    const int nSampBlocks = 8 * 16 * 49;         // 6272 (4 p per block)

    if (ws_size >= tierB) {
        unsigned short* Xb = (unsigned short*)d_ws;
        unsigned short* Wb = Xb + qkvElems;
        unsigned short* k  = Wb + 3 * wElems;
        unsigned short* v  = k + qkvElems;
        unsigned short* qb = (ws_size >= tierA) ? (v + qkvElems) : nullptr;
        float* cgrid = (ws_size >= tierC && qb != nullptr)
                           ? (float*)(qb + qkvElems) : nullptr;
        float* qf = (qb == nullptr) ? out : nullptr;

        const int nbX = (int)(qkvElems / 8 / 256);   // 9408
        const int nbW = (int)(wElems / 8 / 256);     // 288
        const int nConv = nbX + 3 * nbW;             // 10272
        const int nCvt  = nConv + ((cgrid != nullptr) ? (M / 256) : 0);
        cvt4<<<nCvt, 256, 0, stream>>>(
            x, Wq, Wk, Wv, Xb, Wb, Wb + wElems, Wb + 2 * wElems,
            nbX, nbW, nbW, nbW, normx, normy, ids, avgs, stds, cgrid);

        // 256x256 tiles over M=25088 (98) x N=2304 (9) -> 882 blocks
        gemm_qkv_8ph<<<882, 512, 0, stream>>>(
            Xb, Wb, bq, bk, bv, qf, qb, k, v);

        sample_attend<<<nSampBlocks, 256, 0, stream>>>(
            qf, qb, k, v, normx, normy, ids, avgs, stds, cgrid, out);
    } else {
        unsigned short* k = (unsigned short*)d_ws;
        unsigned short* v = k + qkvElems;

        dim3 gGemm(D / BN, M / BM, 3);
        gemm_qkv_f32<<<gGemm, 256, 0, stream>>>(
            x, Wq, Wk, Wv, bq, bk, bv, out, k, v, M, D, D);

        sample_attend<<<nSampBlocks, 256, 0, stream>>>(
            out, nullptr, k, v, normx, normy, ids, avgs, stds, nullptr, out);
    }
}

// Round 11
// 301.908 us; speedup vs baseline: 1.1951x; 1.0021x over previous
//
#include <hip/hip_runtime.h>
#include <hip/hip_bf16.h>

typedef __attribute__((ext_vector_type(4))) float floatx4;
typedef __attribute__((ext_vector_type(4))) int intx4;
typedef __attribute__((ext_vector_type(8))) short shortx8;
typedef __attribute__((address_space(3))) void as3_void;
typedef const __attribute__((address_space(1))) void as1_void;

__device__ __forceinline__ unsigned short f2bf(float f) {
    unsigned int u; __builtin_memcpy(&u, &f, 4);
    u += 0x7FFFu + ((u >> 16) & 1u);   // RNE
    return (unsigned short)(u >> 16);
}
__device__ __forceinline__ float bf2f(unsigned short h) {
    unsigned int u = ((unsigned int)h) << 16;
    float f; __builtin_memcpy(&f, &u, 4); return f;
}
__device__ __forceinline__ shortx8 pack8(floatx4 lo, floatx4 hi) {
    shortx8 r;
    r[0] = (short)f2bf(lo[0]); r[1] = (short)f2bf(lo[1]);
    r[2] = (short)f2bf(lo[2]); r[3] = (short)f2bf(lo[3]);
    r[4] = (short)f2bf(hi[0]); r[5] = (short)f2bf(hi[1]);
    r[6] = (short)f2bf(hi[2]); r[7] = (short)f2bf(hi[3]);
    return r;
}
__device__ __forceinline__ void ld16(const unsigned short* g, unsigned short* l) {
    __builtin_amdgcn_global_load_lds((as1_void*)g, (as3_void*)l, 16, 0, 0);
}

#define MFMA1(d, a, b) d = __builtin_amdgcn_mfma_f32_16x16x32_bf16(a, b, d, 0, 0, 0)
#define BARm asm volatile("s_barrier" ::: "memory")

// ---------- fp32->bf16 convert + coord precompute (coords FIRST) ----------
// Coord blocks now occupy bid < 98: they are latency-bound (6 scattered
// loads + 2 tanhf per thread) and as grid-tail stragglers they extended the
// kernel; dispatched FIRST their latency hides under the 10272 BW-bound
// conversion blocks. Verbatim math = bit-identical.
__global__ __launch_bounds__(256) void cvt4(
    const float* __restrict__ s0, const float* __restrict__ s1,
    const float* __restrict__ s2, const float* __restrict__ s3,
    unsigned short* __restrict__ d0, unsigned short* __restrict__ d1,
    unsigned short* __restrict__ d2, unsigned short* __restrict__ d3,
    int nb0, int nb1, int nb2, int nb3,
    const float* __restrict__ normx, const float* __restrict__ normy,
    const int* __restrict__ img_ids, const float* __restrict__ avgs,
    const float* __restrict__ stds, float* __restrict__ cgrid)
{
    int bid = blockIdx.x;
    const int nco = (cgrid != nullptr) ? 98 : 0;   // 25088/256 coord blocks
    if (bid >= nco) {
        bid -= nco;
        const float* s; unsigned short* d;
        if (bid < nb0)                  { s = s0; d = d0; }
        else if (bid < nb0 + nb1)       { s = s1; d = d1; bid -= nb0; }
        else if (bid < nb0 + nb1 + nb2) { s = s2; d = d2; bid -= nb0 + nb1; }
        else                            { s = s3; d = d3; bid -= nb0 + nb1 + nb2; }
        const size_t i = ((size_t)bid * 256 + threadIdx.x) * 8;
        const floatx4 lo = *(const floatx4*)(s + i);
        const floatx4 hi = *(const floatx4*)(s + i + 4);
        *(shortx8*)(d + i) = pack8(lo, hi);
        return;
    }
    // ---- coord precompute: idx = b*196 + p ----
    const int idx = bid * 256 + (int)threadIdx.x;   // 0..25087
    const int b = idx / 196, p = idx - b * 196;
    const int id = img_ids[b];
    auto coord = [&](int n) -> float {
        int c = 0;
        if (n >= 196) { n -= 196; c = 1; }
        const float base = (c == 0) ? normx[b * 196 + n] : normy[b * 196 + n];
        const float a = avgs[(size_t)id * 392 + c * 196 + n];
        const float s = stds[(size_t)id * 392 + c * 196 + n];
        return tanhf((base + a) * s);
    };
    const float gx = coord(2 * p);
    const float gy = coord(2 * p + 1);
    const float ix = ((gx + 1.0f) * 14.0f - 1.0f) * 0.5f;
    const float iy = ((gy + 1.0f) * 14.0f - 1.0f) * 0.5f;
    const float x0f = floorf(ix), y0f = floorf(iy);
    const float wx1 = ix - x0f, wx0 = 1.0f - wx1;
    const float wy1 = iy - y0f, wy0 = 1.0f - wy1;
    const int x0 = (int)x0f, y0 = (int)y0f;
    const int xs[4] = {x0, x0 + 1, x0, x0 + 1};
    const int ys[4] = {y0, y0, y0 + 1, y0 + 1};
    const float ws4[4] = {wx0 * wy0, wx1 * wy0, wx0 * wy1, wx1 * wy1};
    floatx4 cwv; intx4 rrv;
    #pragma unroll
    for (int c = 0; c < 4; c++) {
        const bool valid = xs[c] >= 0 && xs[c] <= 13 && ys[c] >= 0 && ys[c] <= 13;
        cwv[c] = valid ? ws4[c] : 0.0f;
        rrv[c] = valid ? (ys[c] * 14 + xs[c]) * 768 : 0;
    }
    float* cg = cgrid + (size_t)idx * 8;
    *(floatx4*)cg = cwv;
    *(intx4*)(cg + 4) = rrv;
}

// ---------- GEMM v8 (FROZEN from round 9): 8-phase + LDS-staged epilogue --
// Measured r9/r10: 113-125us (chip variance), FETCH 79.7 MB (analytic min),
// WRITE 112.9 MB (analytic min), loop conflicts 0, MfmaUtil 29-32%.
__global__ __launch_bounds__(512, 2) void gemm_qkv_8ph(
    const unsigned short* __restrict__ Xb,
    const unsigned short* __restrict__ Wb,   // 3 contiguous 768x768 = 2304x768
    const float* __restrict__ bq, const float* __restrict__ bk,
    const float* __restrict__ bv,
    float* __restrict__ Qf, unsigned short* __restrict__ Qb16,
    unsigned short* __restrict__ Kb, unsigned short* __restrict__ Vb)
{
    __shared__ __attribute__((aligned(16))) unsigned short As[2][2][8192];
    __shared__ __attribute__((aligned(16))) unsigned short Bs[2][2][8192];

    const unsigned orig = blockIdx.x;
    const unsigned xcd = orig & 7u, loc = orig >> 3;
    const unsigned wg = (xcd < 2u ? xcd * 111u : 222u + (xcd - 2u) * 110u) + loc;
    const unsigned yb = wg / 9u;
    const unsigned nb = wg - yb * 9u;

    const int tid  = threadIdx.x;
    const int wave = tid >> 6, lane = tid & 63;
    const int fRow = lane & 15, gq = lane >> 4;
    const int wm2  = wave >> 2;
    const int wn4  = wave & 3;
    const int hB   = wn4 >> 1;
    const int bRow0 = (wn4 & 1) * 64;
    const int mBlock = (int)yb * 256;
    const int nRow0  = (int)nb * 256;

    const int srow0 = tid >> 3;
    const int scol  = ((tid & 7) ^ (srow0 & 7)) * 8;
    const int dOff  = tid * 8;

    auto stA = [&](int t, int h, int db) {
        const unsigned short* s =
            Xb + (size_t)(mBlock + h * 128 + srow0) * 768 + t * 64 + scol;
        unsigned short* d = &As[db][h][dOff];
        ld16(s, d);
        ld16(s + (size_t)64 * 768, d + 4096);
    };
    auto stB = [&](int t, int h, int db) {
        const unsigned short* s =
            Wb + (size_t)(nRow0 + h * 128 + srow0) * 768 + t * 64 + scol;
        unsigned short* d = &Bs[db][h][dOff];
        ld16(s, d);
        ld16(s + (size_t)64 * 768, d + 4096);
    };

    const int rc0 = ((0 + gq) ^ (fRow & 7)) * 8;
    const int rc1 = ((4 + gq) ^ (fRow & 7)) * 8;

    floatx4 acc[8][4] = {};

    auto TILE = [&](int db, auto S0, auto S1, auto S2, auto S3, int ck) {
        shortx8 aF[4][2], bF[4][2];
        const unsigned short* Ah = As[db][wm2];
        const unsigned short* Bh = Bs[db][hB];
        #pragma unroll
        for (int ii = 0; ii < 4; ++ii) {
            const int rb = (ii * 16 + fRow) * 64;
            aF[ii][0] = *(const shortx8*)&Ah[rb + rc0];
            aF[ii][1] = *(const shortx8*)&Ah[rb + rc1];
        }
        #pragma unroll
        for (int nn = 0; nn < 2; ++nn) {
            const int rb = (bRow0 + nn * 16 + fRow) * 64;
            bF[nn][0] = *(const shortx8*)&Bh[rb + rc0];
            bF[nn][1] = *(const shortx8*)&Bh[rb + rc1];
        }
        S0();
        BARm;
        __builtin_amdgcn_s_setprio(1);
        #pragma unroll
        for (int ii = 0; ii < 4; ++ii)
            #pragma unroll
            for (int nn = 0; nn < 2; ++nn) {
                MFMA1(acc[ii][nn], aF[ii][0], bF[nn][0]);
                MFMA1(acc[ii][nn], aF[ii][1], bF[nn][1]);
            }
        __builtin_amdgcn_s_setprio(0);
        BARm;
        #pragma unroll
        for (int nn = 2; nn < 4; ++nn) {
            const int rb = (bRow0 + nn * 16 + fRow) * 64;
            bF[nn][0] = *(const shortx8*)&Bh[rb + rc0];
            bF[nn][1] = *(const shortx8*)&Bh[rb + rc1];
        }
        S1();
        BARm;
        __builtin_amdgcn_s_setprio(1);
        #pragma unroll
        for (int ii = 0; ii < 4; ++ii)
            #pragma unroll
            for (int nn = 2; nn < 4; ++nn) {
                MFMA1(acc[ii][nn], aF[ii][0], bF[nn][0]);
                MFMA1(acc[ii][nn], aF[ii][1], bF[nn][1]);
            }
        __builtin_amdgcn_s_setprio(0);
        BARm;
        #pragma unroll
        for (int ii = 0; ii < 4; ++ii) {
            const int rb = ((ii + 4) * 16 + fRow) * 64;
            aF[ii][0] = *(const shortx8*)&Ah[rb + rc0];
            aF[ii][1] = *(const shortx8*)&Ah[rb + rc1];
        }
        S2();
        BARm;
        __builtin_amdgcn_s_setprio(1);
        #pragma unroll
        for (int ii = 0; ii < 4; ++ii)
            #pragma unroll
            for (int nn = 2; nn < 4; ++nn) {
                MFMA1(acc[4 + ii][nn], aF[ii][0], bF[nn][0]);
                MFMA1(acc[4 + ii][nn], aF[ii][1], bF[nn][1]);
            }
        __builtin_amdgcn_s_setprio(0);
        BARm;
        S3();
        BARm;
        __builtin_amdgcn_s_setprio(1);
        #pragma unroll
        for (int ii = 0; ii < 4; ++ii)
            #pragma unroll
            for (int nn = 0; nn < 2; ++nn) {
                MFMA1(acc[4 + ii][nn], aF[ii][0], bF[nn][0]);
                MFMA1(acc[4 + ii][nn], aF[ii][1], bF[nn][1]);
            }
        __builtin_amdgcn_s_setprio(0);
        if (ck == 4)      { asm volatile("s_waitcnt vmcnt(4)" ::: "memory"); }
        else if (ck == 0) { asm volatile("s_waitcnt vmcnt(0)" ::: "memory"); }
        BARm;
    };

    stA(0, 0, 0); stA(0, 1, 0); stB(0, 0, 0); stB(0, 1, 0);
    asm volatile("" ::: "memory");
    stB(1, 0, 1); stB(1, 1, 1);
    asm volatile("s_waitcnt vmcnt(4)" ::: "memory");
    BARm;

    for (int j = 0; j < 6; ++j) {
        const int t1 = 2 * j + 1, t2 = 2 * j + 2, t3 = 2 * j + 3;
        TILE(0,
             [&] { stA(t1, 0, 1); },
             [&] { stA(t1, 1, 1); },
             [&] { if (t2 < 12) stB(t2, 0, 0); },
             [&] { if (t2 < 12) stB(t2, 1, 0); },
             (j < 5) ? 4 : 0);
        TILE(1,
             [&] { if (t2 < 12) stA(t2, 0, 0); },
             [&] { if (t2 < 12) stA(t2, 1, 0); },
             [&] { if (t3 < 12) stB(t3, 0, 1); },
             [&] { if (t3 < 12) stB(t3, 1, 1); },
             (j < 5) ? 4 : -1);
    }

    const int z = (int)nb / 3;
    const int colBase = ((int)nb - z * 3) * 256 + wn4 * 64;
    const float* bias = (z == 0) ? bq : ((z == 1) ? bk : bv);
    const int rowBase = mBlock + wm2 * 128;
    if (z == 0 && Qb16 == nullptr) {
        #pragma unroll
        for (int n = 0; n < 4; ++n) {
            const int col = colBase + n * 16 + fRow;
            const float bvf = bias[col];
            #pragma unroll
            for (int i = 0; i < 8; ++i)
                #pragma unroll
                for (int r = 0; r < 4; ++r)
                    Qf[(size_t)(rowBase + i * 16 + gq * 4 + r) * 768 + col] =
                        acc[i][n][r] + bvf;
        }
    } else {
        unsigned short* Out = (z == 0) ? Qb16 : ((z == 1) ? Kb : Vb);
        float bvf[4];
        #pragma unroll
        for (int n = 0; n < 4; ++n) bvf[n] = bias[colBase + n * 16 + fRow];
        unsigned short* myLds = (wave < 4)
            ? (&As[0][0][0] + wave * 8192)
            : (&Bs[0][0][0] + (wave - 4) * 8192);
        #pragma unroll
        for (int i = 0; i < 8; ++i)
            #pragma unroll
            for (int n = 0; n < 4; ++n)
                #pragma unroll
                for (int r = 0; r < 4; ++r)
                    myLds[(i * 16 + gq * 4 + r) * 64 + (n * 16 + fRow)] =
                        f2bf(acc[i][n][r] + bvf[n]);
        const int rLane = lane >> 3, cChunk = (lane & 7) * 8;
        #pragma unroll
        for (int it = 0; it < 16; ++it) {
            const int row = it * 8 + rLane;
            const shortx8 vv = *(const shortx8*)&myLds[row * 64 + cChunk];
            *(shortx8*)&Out[(size_t)(rowBase + row) * 768 + colBase + cChunk] = vv;
        }
    }
}

#define BM 128
#define BN 128
#define BK 32

// ---------- fallback GEMM (proven): fp32 src, pack in kernel ----------
__global__ __launch_bounds__(256) void gemm_qkv_f32(
    const float* __restrict__ X,
    const float* __restrict__ Wq, const float* __restrict__ Wk,
    const float* __restrict__ Wv,
    const float* __restrict__ bq, const float* __restrict__ bk,
    const float* __restrict__ bv,
    float* __restrict__ Qf, unsigned short* __restrict__ Kb,
    unsigned short* __restrict__ Vb,
    int M, int N, int K)
{
    __shared__ __attribute__((aligned(16))) unsigned short As[BM * BK];
    __shared__ __attribute__((aligned(16))) unsigned short Bs[BN * BK];

    const float* W;  const float* bias;
    if (blockIdx.z == 0)      { W = Wq; bias = bq; }
    else if (blockIdx.z == 1) { W = Wk; bias = bk; }
    else                      { W = Wv; bias = bv; }

    const int tid  = threadIdx.x;
    const int wave = tid >> 6;
    const int lane = tid & 63;
    const int mBlock = blockIdx.y * BM;
    const int nBlock = blockIdx.x * BN;

    const int sRow = tid >> 1;
    const int sCol = (tid & 1) * 16;
    const float* Ag = X + (size_t)(mBlock + sRow) * K + sCol;
    const float* Bg = W + (size_t)(nBlock + sRow) * K + sCol;
    unsigned short* Al = &As[sRow * BK + sCol];
    unsigned short* Bl = &Bs[sRow * BK + sCol];

    floatx4 acc[4][4] = {};
    const int wm   = (wave >> 1) * 64;
    const int wn   = (wave & 1) * 64;
    const int fRow = lane & 15;
    const int fK   = (lane >> 4) * 8;

    for (int kt = 0; kt < K; kt += BK) {
        floatx4 a[4], b[4];
        #pragma unroll
        for (int c = 0; c < 4; c++) {
            a[c] = *(const floatx4*)(Ag + kt + c * 4);
            b[c] = *(const floatx4*)(Bg + kt + c * 4);
        }
        __syncthreads();
        *(shortx8*)(Al)     = pack8(a[0], a[1]);
        *(shortx8*)(Al + 8) = pack8(a[2], a[3]);
        *(shortx8*)(Bl)     = pack8(b[0], b[1]);
        *(shortx8*)(Bl + 8) = pack8(b[2], b[3]);
        __syncthreads();

        shortx8 af[4], bfr[4];
        #pragma unroll
        for (int i = 0; i < 4; i++) {
            af[i]  = *(const shortx8*)&As[(wm + i*16 + fRow) * BK + fK];
            bfr[i] = *(const shortx8*)&Bs[(wn + i*16 + fRow) * BK + fK];
        }
        #pragma unroll
        for (int i = 0; i < 4; i++)
            #pragma unroll
            for (int j = 0; j < 4; j++)
                acc[i][j] = __builtin_amdgcn_mfma_f32_16x16x32_bf16(
                    af[i], bfr[j], acc[i][j], 0, 0, 0);
    }

    const int cRow = (lane >> 4) * 4;
    const int cCol = lane & 15;
    if (blockIdx.z == 0) {
        #pragma unroll
        for (int j = 0; j < 4; j++) {
            const int col = nBlock + wn + j*16 + cCol;
            const float bvf = bias[col];
            #pragma unroll
            for (int i = 0; i < 4; i++)
                #pragma unroll
                for (int r = 0; r < 4; r++)
                    Qf[(size_t)(mBlock + wm + i*16 + cRow + r) * N + col] =
                        acc[i][j][r] + bvf;
        }
    } else {
        unsigned short* Out = (blockIdx.z == 1) ? Kb : Vb;
        #pragma unroll
        for (int j = 0; j < 4; j++) {
            const int col = nBlock + wn + j*16 + cCol;
            const float bvf = bias[col];
            #pragma unroll
            for (int i = 0; i < 4; i++)
                #pragma unroll
                for (int r = 0; r < 4; r++)
                    Out[(size_t)(mBlock + wm + i*16 + cRow + r) * N + col] =
                        f2bf(acc[i][j][r] + bvf);
        }
    }
}

// ---------- sampler v4: q issued before cgrid (deeper MLP window) ----------
// q's address is known immediately; cgrid gates the 16 gathers by a full
// round trip. Issuing q first overlaps its latency under the cgrid->gather
// chain. Inline-coord fallback unchanged.
__global__ __launch_bounds__(256) void sample_attend(
    const float* __restrict__ Qf,            // fp32 q (if Qb16 == null)
    const unsigned short* __restrict__ Qb16, // bf16 q (preferred)
    const unsigned short* __restrict__ Kb,
    const unsigned short* __restrict__ Vb,
    const float* __restrict__ normx,
    const float* __restrict__ normy,
    const int* __restrict__ img_ids,
    const float* __restrict__ avgs,
    const float* __restrict__ stds,
    const float* __restrict__ cgrid,         // precomputed {cw[4], rr[4]} or null
    float* __restrict__ out)
{
    const unsigned g    = blockIdx.x;            // 0..6271
    const unsigned xcd  = g & 7;
    const unsigned slot = g >> 3;                // 0..783
    const int b = (int)(xcd * 16 + (15 - slot / 49));
    const int p = (int)((slot % 49) * 4 + (threadIdx.x >> 6));
    const int lane = threadIdx.x & 63;

    const size_t rowOff = ((size_t)b * 196 + p) * 768;
    const int d0 = lane * 8;                     // elems [d0, d0+8)
    const int d1 = 512 + lane * 4;               // elems [d1, d1+4)

    // ---- q raw loads FIRST (independent of cgrid round trip) ----
    shortx8 q16{}; unsigned long long q8 = 0;
    floatx4 qa{}, qb2{}, qc{};
    if (Qb16 != nullptr) {
        q16 = *(const shortx8*)&Qb16[rowOff + d0];
        q8  = *(const unsigned long long*)&Qb16[rowOff + d1];
    } else {
        qa  = *(const floatx4*)&Qf[rowOff + d0];
        qb2 = *(const floatx4*)&Qf[rowOff + d0 + 4];
        qc  = *(const floatx4*)&Qf[rowOff + d1];
    }

    float cw[4]; int rr[4];
    if (cgrid != nullptr) {
        const float* cg = cgrid + (size_t)(b * 196 + p) * 8;
        const floatx4 cwv = *(const floatx4*)cg;
        const intx4 rrv = *(const intx4*)(cg + 4);
        #pragma unroll
        for (int c = 0; c < 4; c++) { cw[c] = cwv[c]; rr[c] = rrv[c]; }
    } else {
        const int id = img_ids[b];
        auto coord = [&](int n) -> float {
            int c = 0;
            if (n >= 196) { n -= 196; c = 1; }
            const float base = (c == 0) ? normx[b * 196 + n] : normy[b * 196 + n];
            const float a = avgs[(size_t)id * 392 + c * 196 + n];
            const float s = stds[(size_t)id * 392 + c * 196 + n];
            return tanhf((base + a) * s);
        };
        const float gx = coord(2 * p);
        const float gy = coord(2 * p + 1);
        const float ix = ((gx + 1.0f) * 14.0f - 1.0f) * 0.5f;
        const float iy = ((gy + 1.0f) * 14.0f - 1.0f) * 0.5f;
        const float x0f = floorf(ix), y0f = floorf(iy);
        const float wx1 = ix - x0f, wx0 = 1.0f - wx1;
        const float wy1 = iy - y0f, wy0 = 1.0f - wy1;
        const int x0 = (int)x0f, y0 = (int)y0f;
        const int xs[4] = {x0, x0 + 1, x0, x0 + 1};
        const int ys[4] = {y0, y0, y0 + 1, y0 + 1};
        const float ws4[4] = {wx0 * wy0, wx1 * wy0, wx0 * wy1, wx1 * wy1};
        #pragma unroll
        for (int c = 0; c < 4; c++) {
            const bool valid = xs[c] >= 0 && xs[c] <= 13 && ys[c] >= 0 && ys[c] <= 13;
            cw[c] = valid ? ws4[c] : 0.0f;
            rr[c] = valid ? (ys[c] * 14 + xs[c]) * 768 : 0;
        }
    }

    const unsigned short* kb = Kb + (size_t)b * 196 * 768;
    const unsigned short* vb = Vb + (size_t)b * 196 * 768;

    // ---- gather all corner streams (independent loads, MLP-friendly) ----
    shortx8 k16[4], v16[4];
    unsigned long long k8[4], v8[4];
    #pragma unroll
    for (int c = 0; c < 4; c++) {
        k16[c] = *(const shortx8*)&kb[rr[c] + d0];
        v16[c] = *(const shortx8*)&vb[rr[c] + d0];
        k8[c]  = *(const unsigned long long*)&kb[rr[c] + d1];
        v8[c]  = *(const unsigned long long*)&vb[rr[c] + d1];
    }

    float q[12];
    if (Qb16 != nullptr) {
        #pragma unroll
        for (int e = 0; e < 8; e++) q[e] = bf2f((unsigned short)q16[e]);
        #pragma unroll
        for (int e = 0; e < 4; e++) q[8 + e] = bf2f((unsigned short)(q8 >> (16 * e)));
    } else {
        #pragma unroll
        for (int e = 0; e < 4; e++) { q[e] = qa[e]; q[4 + e] = qb2[e]; q[8 + e] = qc[e]; }
    }

    float kx[12] = {}, vx[12] = {};
    #pragma unroll
    for (int c = 0; c < 4; c++) {
        #pragma unroll
        for (int e = 0; e < 8; e++) {
            kx[e] += cw[c] * bf2f((unsigned short)k16[c][e]);
            vx[e] += cw[c] * bf2f((unsigned short)v16[c][e]);
        }
        #pragma unroll
        for (int e = 0; e < 4; e++) {
            kx[8 + e] += cw[c] * bf2f((unsigned short)(k8[c] >> (16 * e)));
            vx[8 + e] += cw[c] * bf2f((unsigned short)(v8[c] >> (16 * e)));
        }
    }

    float partial = 0.0f;
    #pragma unroll
    for (int e = 0; e < 12; e++) partial += kx[e] * q[e];

    #pragma unroll
    for (int off = 32; off >= 1; off >>= 1)
        partial += __shfl_xor(partial, off, 64);
    const float sig = 1.0f / (1.0f + expf(-0.01f * partial));

    floatx4 o0, o1, o2;
    #pragma unroll
    for (int e = 0; e < 4; e++) {
        o0[e] = sig * vx[e];
        o1[e] = sig * vx[4 + e];
        o2[e] = sig * vx[8 + e];
    }
    *(floatx4*)&out[rowOff + d0]     = o0;
    *(floatx4*)&out[rowOff + d0 + 4] = o1;
    *(floatx4*)&out[rowOff + d1]     = o2;
}

extern "C" void kernel_launch(void* const* d_in, const int* in_sizes, int n_in,
                              void* d_out, int out_size, void* d_ws, size_t ws_size,
                              hipStream_t stream) {
    const float* x     = (const float*)d_in[0];
    const int*   ids   = (const int*)d_in[1];
    // d_in[2] = mask (unused by reference)
    const float* normx = (const float*)d_in[3];
    const float* normy = (const float*)d_in[4];
    const float* Wq    = (const float*)d_in[5];
    const float* bq    = (const float*)d_in[6];
    const float* Wk    = (const float*)d_in[7];
    const float* bk    = (const float*)d_in[8];
    const float* Wv    = (const float*)d_in[9];
    const float* bv    = (const float*)d_in[10];
    const float* avgs  = (const float*)d_in[11];
    const float* stds  = (const float*)d_in[12];
    float* out = (float*)d_out;

    const int B = 128, P = 196, D = 768;
    const int M = B * P;                         // 25088
    const size_t qkvElems = (size_t)M * D;       // 19,267,584
    const size_t wElems   = (size_t)D * D;       // 589,824
    const size_t coordFl  = (size_t)M * 8;       // cw[4]+rr[4] per (b,p)

    // ws tiers (deterministic: ws_size constant across calls)
    const size_t tierA = (4 * qkvElems + 3 * wElems) * 2;      // +bf16 q (~157.7 MB)
    const size_t tierC = tierA + coordFl * 4;                  // +coord grid (~158.5 MB)
    const size_t tierB = (3 * qkvElems + 3 * wElems) * 2;      // bf16 X/W/k/v (~119 MB)

    const int nSampBlocks = 8 * 16 * 49;         // 6272 (4 p per block)

    if (ws_size >= tierB) {
        unsigned short* Xb = (unsigned short*)d_ws;
        unsigned short* Wb = Xb + qkvElems;
        unsigned short* k  = Wb + 3 * wElems;
        unsigned short* v  = k + qkvElems;
        unsigned short* qb = (ws_size >= tierA) ? (v + qkvElems) : nullptr;
        float* cgrid = (ws_size >= tierC && qb != nullptr)
                           ? (float*)(qb + qkvElems) : nullptr;
        float* qf = (qb == nullptr) ? out : nullptr;

        const int nbX = (int)(qkvElems / 8 / 256);   // 9408
        const int nbW = (int)(wElems / 8 / 256);     // 288
        const int nConv = nbX + 3 * nbW;             // 10272
        const int nCvt  = nConv + ((cgrid != nullptr) ? (M / 256) : 0);
        cvt4<<<nCvt, 256, 0, stream>>>(
            x, Wq, Wk, Wv, Xb, Wb, Wb + wElems, Wb + 2 * wElems,
            nbX, nbW, nbW, nbW, normx, normy, ids, avgs, stds, cgrid);

        // 256x256 tiles over M=25088 (98) x N=2304 (9) -> 882 blocks
        gemm_qkv_8ph<<<882, 512, 0, stream>>>(
            Xb, Wb, bq, bk, bv, qf, qb, k, v);

        sample_attend<<<nSampBlocks, 256, 0, stream>>>(
            qf, qb, k, v, normx, normy, ids, avgs, stds, cgrid, out);
    } else {
        unsigned short* k = (unsigned short*)d_ws;
        unsigned short* v = k + qkvElems;

        dim3 gGemm(D / BN, M / BM, 3);
        gemm_qkv_f32<<<gGemm, 256, 0, stream>>>(
            x, Wq, Wk, Wv, bq, bk, bv, out, k, v, M, D, D);

        sample_attend<<<nSampBlocks, 256, 0, stream>>>(
            out, nullptr, k, v, normx, normy, ids, avgs, stds, nullptr, out);
    }
}